// Round 2
// baseline (1611.891 us; speedup 1.0000x reference)
//
#include <hip/hip_runtime.h>

// GraphNN: 3 weighted-scatter GCN layers -> edge MLP (decomposed via P/Q node
// GEMMs) -> 2x graph-norm (per-graph affine folded into weights) -> pair
// min/argmin -> per-graph softmax.
//
// ws layout (floats), total ~28.3M floats = 113 MB:
//   x1(1.6M) x2(3.2M) x3(6.4M) agg(3.2M) P(6.4M) Qb(6.4M)
//   S0(12800) Q0s(12800) W1k(819200) gam(6400) S1(6400) Q1s(6400)
//   ug(6400) cg(100) vals(200000)

#define N_NODES 50000
#define N_EDGES 400000
#define N_PAIRS 200000
#define N_G     100
#define EPG     4000
#define PPG     2000

// ---------------- GNN scatter: agg[dst] += x[src] * (w0+w1) per pair ----------
template<int DIN>
__global__ void k_scatter(const int* __restrict__ edges, const float* __restrict__ ea,
                          const float* __restrict__ xin, float* __restrict__ agg) {
    int idx = blockIdx.x * blockDim.x + threadIdx.x;
    if (idx >= N_PAIRS * DIN) return;
    int p = idx / DIN, k = idx % DIN;
    int e = 2 * p;
    int s = edges[e], d = edges[N_EDGES + e];
    float w = ea[2 * e] + ea[2 * e + 2];           // weights of the two dup edges
    atomicAdd(&agg[d * DIN + k], xin[s * DIN + k] * w);
}

// ---------------- dense: xout = tanh(agg@Wrel + brel + xin@Wroot) -------------
template<int DIN, int DOUT, int NITER>
__global__ __launch_bounds__(256) void k_dense(
    const float* __restrict__ xin, const float* __restrict__ agg,
    const float* __restrict__ Wrel, const float* __restrict__ brel,
    const float* __restrict__ Wroot, float* __restrict__ xout) {
    __shared__ float wr[DIN * DOUT], wt[DIN * DOUT], bb[DOUT];
    constexpr int NPI = 256 / DOUT;
    __shared__ float sa[NPI][DIN], sx[NPI][DIN];
    for (int i = threadIdx.x; i < DIN * DOUT; i += 256) { wr[i] = Wrel[i]; wt[i] = Wroot[i]; }
    if (threadIdx.x < DOUT) bb[threadIdx.x] = brel[threadIdx.x];
    int j = threadIdx.x % DOUT;
    int nl = threadIdx.x / DOUT;
    for (int it = 0; it < NITER; ++it) {
        int nb = (blockIdx.x * NITER + it) * NPI;
        __syncthreads();
        for (int i = threadIdx.x; i < NPI * DIN; i += 256) {
            int nn = nb + i / DIN; int kk = i % DIN;
            float av = 0.f, xv = 0.f;
            if (nn < N_NODES) { av = agg[nn * DIN + kk]; xv = xin[nn * DIN + kk]; }
            sa[i / DIN][kk] = av; sx[i / DIN][kk] = xv;
        }
        __syncthreads();
        int n = nb + nl;
        if (n < N_NODES) {
            float acc = bb[j];
            #pragma unroll
            for (int k = 0; k < DIN; ++k)
                acc += sa[nl][k] * wr[k * DOUT + j] + sx[nl][k] * wt[k * DOUT + j];
            xout[n * DOUT + j] = tanhf(acc);
        }
    }
}

// ---------------- P/Q: out[n][j] = sum_k x3[n][k] * W[k*128+j] ----------------
template<int NITER>
__global__ __launch_bounds__(256) void k_affine128(
    const float* __restrict__ xin, const float* __restrict__ W, float* __restrict__ out) {
    __shared__ float ws_[128 * 128];
    __shared__ float sx[2][128];
    for (int i = threadIdx.x; i < 128 * 128; i += 256) ws_[i] = W[i];
    int j = threadIdx.x % 128, nl = threadIdx.x / 128;
    for (int it = 0; it < NITER; ++it) {
        int nb = (blockIdx.x * NITER + it) * 2;
        __syncthreads();
        for (int i = threadIdx.x; i < 2 * 128; i += 256) {
            int nn = nb + i / 128;
            sx[i / 128][i % 128] = (nn < N_NODES) ? xin[nn * 128 + (i % 128)] : 0.f;
        }
        __syncthreads();
        int n = nb + nl;
        if (n < N_NODES) {
            float acc = 0.f;
            #pragma unroll
            for (int k = 0; k < 128; ++k) acc += sx[nl][k] * ws_[k * 128 + j];
            out[n * 128 + j] = acc;
        }
    }
}

// ---------------- h0 stats: per-graph sum/sumsq of tanh(P[s]+Q[d]+w*Wm+b) -----
__global__ __launch_bounds__(128) void k_h0stats(
    const int* __restrict__ edges, const float* __restrict__ ea,
    const float* __restrict__ P, const float* __restrict__ Qb,
    const float* __restrict__ Wd0, const float* __restrict__ bd0,
    float* __restrict__ S0, float* __restrict__ Q0s) {
    int g = blockIdx.x >> 3, part = blockIdx.x & 7;
    int j = threadIdx.x;
    float wm = Wd0[128 * 128 + j];
    float b = bd0[j];
    float s = 0.f, q = 0.f;
    int e0 = g * EPG + part * 500;
    for (int t = 0; t < 500; ++t) {
        int e = e0 + t;
        int sn = edges[e], dn = edges[N_EDGES + e];
        float w = ea[2 * e];
        float h = tanhf(P[sn * 128 + j] + Qb[dn * 128 + j] + w * wm + b);
        s += h; q += h * h;
    }
    atomicAdd(&S0[g * 128 + j], s);
    atomicAdd(&Q0s[g * 128 + j], q);
}

// ---------------- fold gnorm0 into Wd1: W1k[g][k][j] = a0[g,k]*Wd1[k][j] ------
__global__ __launch_bounds__(256) void k_fin0(
    const float* __restrict__ S0, const float* __restrict__ Q0s,
    const float* __restrict__ gnw, const float* __restrict__ gnb, const float* __restrict__ gnms,
    const float* __restrict__ Wd1, const float* __restrict__ bd1,
    float* __restrict__ W1k, float* __restrict__ gam) {
    int g = blockIdx.x;
    __shared__ float al[128], be[128];
    if (threadIdx.x < 128) {
        int k = threadIdx.x;
        float S = S0[g * 128 + k], Q = Q0s[g * 128 + k];
        float mean = S * (1.f / EPG);
        float t = mean * gnms[k];
        float var = (Q - 2.f * t * S) * (1.f / EPG) + t * t;
        float a = gnw[k] * rsqrtf(var + 1e-5f);
        al[k] = a;
        be[k] = gnb[k] - a * t;
    }
    __syncthreads();
    for (int i = threadIdx.x; i < 128 * 64; i += 256) {
        int k = i >> 6;
        W1k[g * 8192 + i] = al[k] * Wd1[i];
    }
    if (threadIdx.x < 64) {
        int j = threadIdx.x;
        float acc = bd1[j];
        #pragma unroll 8
        for (int k = 0; k < 128; ++k) acc += be[k] * Wd1[k * 64 + j];
        gam[g * 64 + j] = acc;
    }
}

// ---------------- h1 pass (templated): stats OR final vals --------------------
// block = 4 waves x 64 lanes; each wave handles 25 pairs of one graph serially.
// Per thread: one h1 feature column (128 folded weights in VGPRs);
// h0 broadcast via per-wave LDS float4 buffer.
template<int DO_VALS>
__global__ __launch_bounds__(256, 2) void k_h1(
    const int* __restrict__ edges, const float* __restrict__ ea,
    const float* __restrict__ P, const float* __restrict__ Qb,
    const float* __restrict__ Wd0, const float* __restrict__ bd0,
    const float* __restrict__ W1k, const float* __restrict__ gam,
    const float* __restrict__ ug, const float* __restrict__ cg,
    float* __restrict__ S1, float* __restrict__ Q1s,
    float* __restrict__ vals, float* __restrict__ outp) {
    __shared__ float4 h0buf[4][32];
    __shared__ float red[2][4][64];
    int g = blockIdx.x / 20, sub = blockIdx.x % 20;
    int wave = threadIdx.x >> 6, j = threadIdx.x & 63;

    float wreg[128];
    const float* wsrc = W1k + g * 8192;
    #pragma unroll
    for (int k = 0; k < 128; ++k) wreg[k] = wsrc[k * 64 + j];   // coalesced

    float gm = gam[g * 64 + j];
    float wm0 = Wd0[16384 + j], wm1 = Wd0[16384 + 64 + j];
    float b0 = bd0[j], b1 = bd0[64 + j];
    float uj = 0.f, cgv = 0.f;
    if (DO_VALS) { uj = ug[g * 64 + j]; cgv = cg[g]; }
    float s_acc = 0.f, q_acc = 0.f;
    int pbase = g * PPG + sub * 100 + wave * 25;
    float* hb = (float*)&h0buf[wave][0];
    float v0 = 0.f;

    for (int pp = 0; pp < 25; ++pp) {
        int pi = pbase + pp;
        for (int par = 0; par < 2; ++par) {
            int e = 2 * pi + par;
            int sn = edges[e], dn = edges[N_EDGES + e];
            float w = ea[2 * e];
            float a0 = tanhf(P[sn * 128 + j]      + Qb[dn * 128 + j]      + w * wm0 + b0);
            float a1 = tanhf(P[sn * 128 + 64 + j] + Qb[dn * 128 + 64 + j] + w * wm1 + b1);
            hb[j] = a0; hb[64 + j] = a1;       // per-wave buffer, in-order DS pipe
            float acc0 = 0.f, acc1 = 0.f, acc2 = 0.f, acc3 = 0.f;
            #pragma unroll
            for (int k4 = 0; k4 < 32; ++k4) {
                float4 h = h0buf[wave][k4];     // uniform address -> broadcast
                acc0 += h.x * wreg[4 * k4 + 0];
                acc1 += h.y * wreg[4 * k4 + 1];
                acc2 += h.z * wreg[4 * k4 + 2];
                acc3 += h.w * wreg[4 * k4 + 3];
            }
            float h1 = tanhf((acc0 + acc1) + (acc2 + acc3) + gm);
            if (DO_VALS) {
                float v = h1 * uj;
                #pragma unroll
                for (int off = 32; off; off >>= 1) v += __shfl_xor(v, off);
                v += cgv;
                if (par == 0) v0 = v;
                else if (j == 0) {
                    int ind = (v < v0) ? 1 : 0;                 // argmin, first-min
                    vals[pi] = fminf(v0, v);
                    outp[600000 + pi] = ea[2 * (2 * pi + ind) + 1];   // edge class
                    outp[pi]          = (float)edges[2 * pi];          // src row
                    outp[200000 + pi] = (float)edges[N_EDGES + 2 * pi];// dst row
                }
            } else {
                s_acc += h1; q_acc += h1 * h1;
            }
        }
    }
    if (!DO_VALS) {
        red[0][wave][j] = s_acc; red[1][wave][j] = q_acc;
        __syncthreads();
        if (threadIdx.x < 64) {
            float s = red[0][0][j] + red[0][1][j] + red[0][2][j] + red[0][3][j];
            float q = red[1][0][j] + red[1][1][j] + red[1][2][j] + red[1][3][j];
            atomicAdd(&S1[g * 64 + j], s);
            atomicAdd(&Q1s[g * 64 + j], q);
        }
    }
}

// ---------------- fold gnorm1 into Wout: ug = a1.*Wout, cg = be1.Wout+bout ----
__global__ void k_fin1(const float* __restrict__ S1, const float* __restrict__ Q1s,
                       const float* __restrict__ gnw, const float* __restrict__ gnb,
                       const float* __restrict__ gnms,
                       const float* __restrict__ Wout, const float* __restrict__ bout,
                       float* __restrict__ ug, float* __restrict__ cg) {
    int g = blockIdx.x; int j = threadIdx.x;  // 64 threads
    float S = S1[g * 64 + j], Q = Q1s[g * 64 + j];
    float mean = S * (1.f / EPG);
    float t = mean * gnms[j];
    float var = (Q - 2.f * t * S) * (1.f / EPG) + t * t;
    float a = gnw[j] * rsqrtf(var + 1e-5f);
    float b = gnb[j] - a * t;
    ug[g * 64 + j] = a * Wout[j];
    float c = b * Wout[j];
    #pragma unroll
    for (int off = 32; off; off >>= 1) c += __shfl_xor(c, off);
    if (j == 0) cg[g] = c + bout[0];
}

// ---------------- per-graph softmax over pair-min vals ------------------------
__global__ __launch_bounds__(256) void k_softmax(const float* __restrict__ vals,
                                                 float* __restrict__ outp) {
    int g = blockIdx.x;
    __shared__ float rbuf[4], rbuf2[4];
    int t = threadIdx.x;
    const float* v = vals + g * PPG;
    float mx = -1e30f;
    for (int i = t; i < PPG; i += 256) mx = fmaxf(mx, v[i]);
    #pragma unroll
    for (int off = 32; off; off >>= 1) mx = fmaxf(mx, __shfl_xor(mx, off));
    if ((t & 63) == 0) rbuf[t >> 6] = mx;
    __syncthreads();
    mx = fmaxf(fmaxf(rbuf[0], rbuf[1]), fmaxf(rbuf[2], rbuf[3]));
    float sm = 0.f;
    for (int i = t; i < PPG; i += 256) sm += expf(v[i] - mx);
    #pragma unroll
    for (int off = 32; off; off >>= 1) sm += __shfl_xor(sm, off);
    if ((t & 63) == 0) rbuf2[t >> 6] = sm;
    __syncthreads();
    sm = rbuf2[0] + rbuf2[1] + rbuf2[2] + rbuf2[3];
    for (int i = t; i < PPG; i += 256)
        outp[400000 + g * PPG + i] = expf(v[i] - mx) / (sm + 1e-16f);
}

extern "C" void kernel_launch(void* const* d_in, const int* in_sizes, int n_in,
                              void* d_out, int out_size, void* d_ws, size_t ws_size,
                              hipStream_t stream) {
    const float* x     = (const float*)d_in[0];
    const int*   edges = (const int*)d_in[1];
    const float* ea    = (const float*)d_in[2];
    const float* Wrel0 = (const float*)d_in[6],  *brel0 = (const float*)d_in[7],  *Wroot0 = (const float*)d_in[8];
    const float* Wrel1 = (const float*)d_in[9],  *brel1 = (const float*)d_in[10], *Wroot1 = (const float*)d_in[11];
    const float* Wrel2 = (const float*)d_in[12], *brel2 = (const float*)d_in[13], *Wroot2 = (const float*)d_in[14];
    const float* Wd0 = (const float*)d_in[15],  *bd0 = (const float*)d_in[16];
    const float* gnw0 = (const float*)d_in[17], *gnb0 = (const float*)d_in[18], *gnms0 = (const float*)d_in[19];
    const float* Wd1 = (const float*)d_in[20],  *bd1 = (const float*)d_in[21];
    const float* gnw1 = (const float*)d_in[22], *gnb1 = (const float*)d_in[23], *gnms1 = (const float*)d_in[24];
    const float* Wout = (const float*)d_in[25], *bout = (const float*)d_in[26];
    float* o = (float*)d_out;
    float* w = (float*)d_ws;

    float* x1  = w;
    float* x2  = x1 + 1600000;
    float* x3  = x2 + 3200000;
    float* agg = x3 + 6400000;
    float* P   = agg + 3200000;
    float* Qb  = P + 6400000;
    float* S0  = Qb + 6400000;
    float* Q0s = S0 + 12800;
    float* W1k = Q0s + 12800;
    float* gam = W1k + 819200;
    float* S1  = gam + 6400;
    float* Q1s = S1 + 6400;
    float* ug  = Q1s + 6400;
    float* cg  = ug + 6400;
    float* vals = cg + 100;

    // ---- 3 GCN layers ----
    hipMemsetAsync(agg, 0, (size_t)N_NODES * 5 * sizeof(float), stream);
    k_scatter<5><<<(N_PAIRS * 5 + 255) / 256, 256, 0, stream>>>(edges, ea, x, agg);
    k_dense<5, 32, 8><<<(N_NODES + 63) / 64, 256, 0, stream>>>(x, agg, Wrel0, brel0, Wroot0, x1);

    hipMemsetAsync(agg, 0, (size_t)N_NODES * 32 * sizeof(float), stream);
    k_scatter<32><<<(N_PAIRS * 32 + 255) / 256, 256, 0, stream>>>(edges, ea, x1, agg);
    k_dense<32, 64, 8><<<(N_NODES + 31) / 32, 256, 0, stream>>>(x1, agg, Wrel1, brel1, Wroot1, x2);

    hipMemsetAsync(agg, 0, (size_t)N_NODES * 64 * sizeof(float), stream);
    k_scatter<64><<<(N_PAIRS * 64 + 255) / 256, 256, 0, stream>>>(edges, ea, x2, agg);
    k_dense<64, 128, 8><<<(N_NODES + 15) / 16, 256, 0, stream>>>(x2, agg, Wrel2, brel2, Wroot2, x3);

    // ---- P/Q decomposition of the 257-wide edge GEMM ----
    k_affine128<16><<<(N_NODES + 31) / 32, 256, 0, stream>>>(x3, Wd0, P);            // rows 0..127
    k_affine128<16><<<(N_NODES + 31) / 32, 256, 0, stream>>>(x3, Wd0 + 129 * 128, Qb); // rows 129..256

    // ---- gnorm0 stats + fold into Wd1 ----
    hipMemsetAsync(S0, 0, 25600 * sizeof(float), stream);
    k_h0stats<<<N_G * 8, 128, 0, stream>>>(edges, ea, P, Qb, Wd0, bd0, S0, Q0s);
    k_fin0<<<N_G, 256, 0, stream>>>(S0, Q0s, gnw0, gnb0, gnms0, Wd1, bd1, W1k, gam);

    // ---- h1 stats pass, fold gnorm1 into Wout, final vals pass ----
    hipMemsetAsync(S1, 0, 12800 * sizeof(float), stream);
    k_h1<0><<<N_G * 20, 256, 0, stream>>>(edges, ea, P, Qb, Wd0, bd0, W1k, gam,
                                          ug, cg, S1, Q1s, vals, o);
    k_fin1<<<N_G, 64, 0, stream>>>(S1, Q1s, gnw1, gnb1, gnms1, Wout, bout, ug, cg);
    k_h1<1><<<N_G * 20, 256, 0, stream>>>(edges, ea, P, Qb, Wd0, bd0, W1k, gam,
                                          ug, cg, S1, Q1s, vals, o);

    // ---- per-graph softmax ----
    k_softmax<<<N_G, 256, 0, stream>>>(vals, o);
}

// Round 3
// 890.234 us; speedup vs baseline: 1.8106x; 1.8106x over previous
//
#include <hip/hip_runtime.h>

// GraphNN: 3 weighted-scatter GCN layers (LDS per-graph scatter) -> edge MLP
// decomposed via P/Q node GEMMs (bd0 folded into P) -> gnorm0 folded into
// bf16 frag-packed W1 -> MFMA edge GEMM (h1) -> gnorm1 folded into Wout ->
// pair min/argmin (class = argmin index, since classes are [0,1] per pair)
// -> per-graph softmax.

#define N_NODES 50000
#define N_EDGES 400000
#define N_PAIRS 200000
#define N_G     100
#define EPG     4000
#define PPG     2000

typedef float  f4   __attribute__((ext_vector_type(4)));
typedef short  bf8  __attribute__((ext_vector_type(8)));
typedef unsigned u32x4 __attribute__((ext_vector_type(4)));

__device__ __forceinline__ float tanh_fast(float x) {
    float cx = fminf(15.f, fmaxf(-15.f, x));
    float e = __expf(2.f * cx);
    return (e - 1.f) * __builtin_amdgcn_rcpf(e + 1.f);
}
__device__ __forceinline__ unsigned f2bf(float f) {   // RNE fp32->bf16
    unsigned u = __float_as_uint(f);
    return (u + 0x7FFFu + ((u >> 16) & 1u)) >> 16;
}

// ---------------- GNN scatter via per-graph LDS: agg[dst] += x[src]*(w0+w1) --
template<int DIN, int FCH>
__global__ __launch_bounds__(256) void k_scatter2(
    const int* __restrict__ edges, const float* __restrict__ ea,
    const float* __restrict__ xin, float* __restrict__ agg) {
    __shared__ float s[500 * FCH];
    constexpr int NB = DIN / FCH;
    int g = blockIdx.x / NB, fc = blockIdx.x % NB, f0 = fc * FCH;
    for (int i = threadIdx.x; i < 500 * FCH; i += 256) s[i] = 0.f;
    __syncthreads();
    int p0 = g * PPG;
    for (int i = threadIdx.x; i < PPG * FCH; i += 256) {
        int p = p0 + i / FCH, f = i % FCH;
        int e = 2 * p;
        int sn = edges[e], dn = edges[N_EDGES + e];
        float wv = ea[2 * e] + ea[2 * e + 2];
        atomicAdd(&s[(dn - g * 500) * FCH + f], xin[sn * DIN + f0 + f] * wv);
    }
    __syncthreads();
    for (int i = threadIdx.x; i < 500 * FCH; i += 256) {
        int n = i / FCH, f = i % FCH;
        agg[(g * 500 + n) * DIN + f0 + f] = s[i];
    }
}

// ---------------- dense: xout = tanh(agg@Wrel + brel + xin@Wroot) -------------
template<int DIN, int DOUT, int NITER>
__global__ __launch_bounds__(256) void k_dense(
    const float* __restrict__ xin, const float* __restrict__ agg,
    const float* __restrict__ Wrel, const float* __restrict__ brel,
    const float* __restrict__ Wroot, float* __restrict__ xout) {
    __shared__ float wr[DIN * DOUT], wt[DIN * DOUT], bb[DOUT];
    constexpr int NPI = 256 / DOUT;
    __shared__ float sa[NPI][DIN], sx[NPI][DIN];
    for (int i = threadIdx.x; i < DIN * DOUT; i += 256) { wr[i] = Wrel[i]; wt[i] = Wroot[i]; }
    if (threadIdx.x < DOUT) bb[threadIdx.x] = brel[threadIdx.x];
    int j = threadIdx.x % DOUT;
    int nl = threadIdx.x / DOUT;
    for (int it = 0; it < NITER; ++it) {
        int nb = (blockIdx.x * NITER + it) * NPI;
        __syncthreads();
        for (int i = threadIdx.x; i < NPI * DIN; i += 256) {
            int nn = nb + i / DIN; int kk = i % DIN;
            float av = 0.f, xv = 0.f;
            if (nn < N_NODES) { av = agg[nn * DIN + kk]; xv = xin[nn * DIN + kk]; }
            sa[i / DIN][kk] = av; sx[i / DIN][kk] = xv;
        }
        __syncthreads();
        int n = nb + nl;
        if (n < N_NODES) {
            float acc = bb[j];
            #pragma unroll
            for (int k = 0; k < DIN; ++k)
                acc += sa[nl][k] * wr[k * DOUT + j] + sx[nl][k] * wt[k * DOUT + j];
            xout[n * DOUT + j] = tanhf(acc);
        }
    }
}

// ---------------- P/Q: out[n][j] = sum_k x3[n][k]*W[k*128+j] (+bias[j]) -------
template<int NITER>
__global__ __launch_bounds__(256) void k_affine128(
    const float* __restrict__ xin, const float* __restrict__ W,
    const float* __restrict__ bias, float* __restrict__ out) {
    __shared__ float ws_[128 * 128];
    __shared__ float sx[2][128];
    for (int i = threadIdx.x; i < 128 * 128; i += 256) ws_[i] = W[i];
    int j = threadIdx.x % 128, nl = threadIdx.x / 128;
    float bv = bias ? bias[j] : 0.f;
    for (int it = 0; it < NITER; ++it) {
        int nb = (blockIdx.x * NITER + it) * 2;
        __syncthreads();
        for (int i = threadIdx.x; i < 2 * 128; i += 256) {
            int nn = nb + i / 128;
            sx[i / 128][i % 128] = (nn < N_NODES) ? xin[nn * 128 + (i % 128)] : 0.f;
        }
        __syncthreads();
        int n = nb + nl;
        if (n < N_NODES) {
            float acc = bv;
            #pragma unroll
            for (int k = 0; k < 128; ++k) acc += sx[nl][k] * ws_[k * 128 + j];
            out[n * 128 + j] = acc;
        }
    }
}

// ---------------- h0 stats: per-graph sum/sumsq of tanh(P[s]+Q[d]+w*wm) ------
// wave handles 32-edge tiles; lane: edge = 16m+(lane&15), k = kk*32+grp*8+r.
__global__ __launch_bounds__(256, 1) void k_h0s(
    const int* __restrict__ edges, const float* __restrict__ ea,
    const float* __restrict__ P, const float* __restrict__ Qb,
    const float* __restrict__ Wd0,
    float* __restrict__ S0, float* __restrict__ Q0s) {
    int g = blockIdx.x >> 3, tb = blockIdx.x & 7;
    int wave = threadIdx.x >> 6, lane = threadIdx.x & 63;
    int row = lane & 15, grp = lane >> 4;
    int slot = tb * 4 + wave;
    f4 wmr[4][2];
    #pragma unroll
    for (int kk = 0; kk < 4; ++kk) {
        const f4* wmp = (const f4*)(Wd0 + 16384 + kk * 32 + grp * 8);
        wmr[kk][0] = wmp[0]; wmr[kk][1] = wmp[1];
    }
    f4 s[4][2], q[4][2];
    #pragma unroll
    for (int kk = 0; kk < 4; ++kk)
        #pragma unroll
        for (int h = 0; h < 2; ++h) { s[kk][h] = (f4)0.f; q[kk][h] = (f4)0.f; }

    for (int j = 0; j < 4; ++j) {
        int tile = slot + 32 * j;
        if (tile >= 125) break;
        int eg0 = g * EPG + tile * 32;
        #pragma unroll
        for (int m = 0; m < 2; ++m) {
            int e = eg0 + 16 * m + row;
            int sn = edges[e], dn = edges[N_EDGES + e];
            float w = ea[2 * e];
            const f4* Pr = (const f4*)(P + sn * 128);
            const f4* Qr = (const f4*)(Qb + dn * 128);
            #pragma unroll
            for (int kk = 0; kk < 4; ++kk) {
                int o = kk * 8 + grp * 2;
                f4 p0 = Pr[o], p1 = Pr[o + 1];
                f4 q0 = Qr[o], q1 = Qr[o + 1];
                #pragma unroll
                for (int r = 0; r < 4; ++r) {
                    float h0 = tanh_fast(p0[r] + q0[r] + w * wmr[kk][0][r]);
                    float h1 = tanh_fast(p1[r] + q1[r] + w * wmr[kk][1][r]);
                    s[kk][0][r] += h0; q[kk][0][r] += h0 * h0;
                    s[kk][1][r] += h1; q[kk][1][r] += h1 * h1;
                }
            }
        }
    }
    #pragma unroll
    for (int kk = 0; kk < 4; ++kk)
        #pragma unroll
        for (int h = 0; h < 2; ++h)
            #pragma unroll
            for (int r = 0; r < 4; ++r) {
                float sv = s[kk][h][r], qv = q[kk][h][r];
                sv += __shfl_xor(sv, 1); sv += __shfl_xor(sv, 2);
                sv += __shfl_xor(sv, 4); sv += __shfl_xor(sv, 8);
                qv += __shfl_xor(qv, 1); qv += __shfl_xor(qv, 2);
                qv += __shfl_xor(qv, 4); qv += __shfl_xor(qv, 8);
                if (row == 0) {
                    int k = kk * 32 + grp * 8 + h * 4 + r;
                    atomicAdd(&S0[g * 128 + k], sv);
                    atomicAdd(&Q0s[g * 128 + k], qv);
                }
            }
}

// ---------------- fold gnorm0 into Wd1 -> bf16 frag-packed W1b + gam ---------
__global__ __launch_bounds__(256) void k_fin0(
    const float* __restrict__ S0, const float* __restrict__ Q0s,
    const float* __restrict__ gnw, const float* __restrict__ gnb, const float* __restrict__ gnms,
    const float* __restrict__ Wd1, const float* __restrict__ bd1,
    unsigned* __restrict__ W1b, float* __restrict__ gam) {
    int g = blockIdx.x;
    __shared__ float al[128], be[128];
    if (threadIdx.x < 128) {
        int k = threadIdx.x;
        float S = S0[g * 128 + k], Q = Q0s[g * 128 + k];
        float mean = S * (1.f / EPG);
        float t = mean * gnms[k];
        float var = (Q - 2.f * t * S) * (1.f / EPG) + t * t;
        float a = gnw[k] * rsqrtf(var + 1e-5f);
        al[k] = a;
        be[k] = gnb[k] - a * t;
    }
    __syncthreads();
    // frag order: word i: t=i&3, l=(i>>2)&63, kk=(i>>8)&3, n=i>>10
    unsigned* Wb = W1b + (size_t)g * 4096;
    for (int i = threadIdx.x; i < 4096; i += 256) {
        int t = i & 3, l = (i >> 2) & 63, kk = (i >> 8) & 3, n = i >> 10;
        int k = kk * 32 + ((l >> 4) << 3) + 2 * t;
        int j = 16 * n + (l & 15);
        unsigned lo = f2bf(al[k] * Wd1[k * 64 + j]);
        unsigned hi = f2bf(al[k + 1] * Wd1[(k + 1) * 64 + j]);
        Wb[i] = lo | (hi << 16);
    }
    if (threadIdx.x < 64) {
        int j = threadIdx.x;
        float acc = bd1[j];
        #pragma unroll 8
        for (int k = 0; k < 128; ++k) acc += be[k] * Wd1[k * 64 + j];
        gam[g * 64 + j] = acc;
    }
}

// ---------------- MFMA h1 pass: stats (DO_VALS=0) or final vals (=1) ---------
// wave = one 32-edge tile per j-iter. A = h0 (bf16, built from P/Q gathers),
// B = W1b frags (persistent). C layout: col=lane&15, row=(lane>>4)*4+reg.
template<int DO_VALS>
__global__ __launch_bounds__(256, 1) void k_h1m(
    const int* __restrict__ edges, const float* __restrict__ ea,
    const float* __restrict__ P, const float* __restrict__ Qb,
    const float* __restrict__ Wd0,
    const unsigned* __restrict__ W1b, const float* __restrict__ gam,
    const float* __restrict__ ug, const float* __restrict__ cg,
    float* __restrict__ S1, float* __restrict__ Q1s,
    float* __restrict__ vals, float* __restrict__ outp) {
    int g = blockIdx.x >> 3, tb = blockIdx.x & 7;
    int wave = threadIdx.x >> 6, lane = threadIdx.x & 63;
    int col = lane & 15, grp = lane >> 4;
    int slot = tb * 4 + wave;

    bf8 bf[4][4];
    {
        const u32x4* Wb = (const u32x4*)(W1b + (size_t)g * 4096);
        #pragma unroll
        for (int n = 0; n < 4; ++n)
            #pragma unroll
            for (int kk = 0; kk < 4; ++kk)
                bf[n][kk] = __builtin_bit_cast(bf8, Wb[(n * 4 + kk) * 64 + lane]);
    }
    f4 wmr[4][2];
    #pragma unroll
    for (int kk = 0; kk < 4; ++kk) {
        const f4* wmp = (const f4*)(Wd0 + 16384 + kk * 32 + grp * 8);
        wmr[kk][0] = wmp[0]; wmr[kk][1] = wmp[1];
    }
    float gamn[4], un[4] = {0.f, 0.f, 0.f, 0.f};
    #pragma unroll
    for (int n = 0; n < 4; ++n) gamn[n] = gam[g * 64 + 16 * n + col];
    float cgv = 0.f;
    if (DO_VALS) {
        #pragma unroll
        for (int n = 0; n < 4; ++n) un[n] = ug[g * 64 + 16 * n + col];
        cgv = cg[g];
    }
    float sacc[4] = {0.f, 0.f, 0.f, 0.f}, qacc[4] = {0.f, 0.f, 0.f, 0.f};

    for (int j = 0; j < 4; ++j) {
        int tile = slot + 32 * j;
        if (tile >= 125) break;
        int eg0 = g * EPG + tile * 32;
        bf8 af[2][4];
        #pragma unroll
        for (int m = 0; m < 2; ++m) {
            int e = eg0 + 16 * m + col;
            int sn = edges[e], dn = edges[N_EDGES + e];
            float w = ea[2 * e];
            const f4* Pr = (const f4*)(P + sn * 128);
            const f4* Qr = (const f4*)(Qb + dn * 128);
            #pragma unroll
            for (int kk = 0; kk < 4; ++kk) {
                int o = kk * 8 + grp * 2;
                f4 p0 = Pr[o], p1 = Pr[o + 1];
                f4 q0 = Qr[o], q1 = Qr[o + 1];
                bf8 a;
                #pragma unroll
                for (int r = 0; r < 4; ++r) {
                    float h0 = tanh_fast(p0[r] + q0[r] + w * wmr[kk][0][r]);
                    float h1 = tanh_fast(p1[r] + q1[r] + w * wmr[kk][1][r]);
                    a[r]     = (short)f2bf(h0);
                    a[4 + r] = (short)f2bf(h1);
                }
                af[m][kk] = a;
            }
        }
        f4 acc[2][4];
        #pragma unroll
        for (int m = 0; m < 2; ++m)
            #pragma unroll
            for (int n = 0; n < 4; ++n) acc[m][n] = (f4)0.f;
        #pragma unroll
        for (int kk = 0; kk < 4; ++kk)
            #pragma unroll
            for (int m = 0; m < 2; ++m)
                #pragma unroll
                for (int n = 0; n < 4; ++n)
                    acc[m][n] = __builtin_amdgcn_mfma_f32_16x16x32_bf16(
                        af[m][kk], bf[n][kk], acc[m][n], 0, 0, 0);

        if (DO_VALS) {
            float rp[2][4];
            #pragma unroll
            for (int m = 0; m < 2; ++m)
                #pragma unroll
                for (int t = 0; t < 4; ++t) {
                    float v = 0.f;
                    #pragma unroll
                    for (int n = 0; n < 4; ++n)
                        v += un[n] * tanh_fast(acc[m][n][t] + gamn[n]);
                    v += __shfl_xor(v, 1); v += __shfl_xor(v, 2);
                    v += __shfl_xor(v, 4); v += __shfl_xor(v, 8);
                    rp[m][t] = v + cgv;
                }
            if (col == 0) {
                #pragma unroll
                for (int m = 0; m < 2; ++m)
                    #pragma unroll
                    for (int pr = 0; pr < 2; ++pr) {
                        float va = rp[m][2 * pr], vb = rp[m][2 * pr + 1];
                        int p = ((eg0 + 16 * m + grp * 4) >> 1) + pr;
                        vals[p] = fminf(va, vb);
                        outp[600000 + p] = (vb < va) ? 1.f : 0.f;   // class = argmin idx
                        int e = 2 * p;
                        outp[p]          = (float)edges[e];
                        outp[200000 + p] = (float)edges[N_EDGES + e];
                    }
            }
        } else {
            #pragma unroll
            for (int m = 0; m < 2; ++m)
                #pragma unroll
                for (int n = 0; n < 4; ++n)
                    #pragma unroll
                    for (int t = 0; t < 4; ++t) {
                        float h = tanh_fast(acc[m][n][t] + gamn[n]);
                        sacc[n] += h; qacc[n] += h * h;
                    }
        }
    }
    if (!DO_VALS) {
        #pragma unroll
        for (int n = 0; n < 4; ++n) {
            float s = sacc[n], q = qacc[n];
            s += __shfl_xor(s, 16); s += __shfl_xor(s, 32);
            q += __shfl_xor(q, 16); q += __shfl_xor(q, 32);
            if (lane < 16) {
                atomicAdd(&S1[g * 64 + 16 * n + col], s);
                atomicAdd(&Q1s[g * 64 + 16 * n + col], q);
            }
        }
    }
}

// ---------------- fold gnorm1 into Wout ---------------------------------------
__global__ void k_fin1(const float* __restrict__ S1, const float* __restrict__ Q1s,
                       const float* __restrict__ gnw, const float* __restrict__ gnb,
                       const float* __restrict__ gnms,
                       const float* __restrict__ Wout, const float* __restrict__ bout,
                       float* __restrict__ ug, float* __restrict__ cg) {
    int g = blockIdx.x; int j = threadIdx.x;  // 64 threads
    float S = S1[g * 64 + j], Q = Q1s[g * 64 + j];
    float mean = S * (1.f / EPG);
    float t = mean * gnms[j];
    float var = (Q - 2.f * t * S) * (1.f / EPG) + t * t;
    float a = gnw[j] * rsqrtf(var + 1e-5f);
    float b = gnb[j] - a * t;
    ug[g * 64 + j] = a * Wout[j];
    float c = b * Wout[j];
    #pragma unroll
    for (int off = 32; off; off >>= 1) c += __shfl_xor(c, off);
    if (j == 0) cg[g] = c + bout[0];
}

// ---------------- per-graph softmax over pair-min vals ------------------------
__global__ __launch_bounds__(256) void k_softmax(const float* __restrict__ vals,
                                                 float* __restrict__ outp) {
    int g = blockIdx.x;
    __shared__ float rbuf[4], rbuf2[4];
    int t = threadIdx.x;
    const float* v = vals + g * PPG;
    float mx = -1e30f;
    for (int i = t; i < PPG; i += 256) mx = fmaxf(mx, v[i]);
    #pragma unroll
    for (int off = 32; off; off >>= 1) mx = fmaxf(mx, __shfl_xor(mx, off));
    if ((t & 63) == 0) rbuf[t >> 6] = mx;
    __syncthreads();
    mx = fmaxf(fmaxf(rbuf[0], rbuf[1]), fmaxf(rbuf[2], rbuf[3]));
    float sm = 0.f;
    for (int i = t; i < PPG; i += 256) sm += expf(v[i] - mx);
    #pragma unroll
    for (int off = 32; off; off >>= 1) sm += __shfl_xor(sm, off);
    if ((t & 63) == 0) rbuf2[t >> 6] = sm;
    __syncthreads();
    sm = rbuf2[0] + rbuf2[1] + rbuf2[2] + rbuf2[3];
    for (int i = t; i < PPG; i += 256)
        outp[400000 + g * PPG + i] = expf(v[i] - mx) / (sm + 1e-16f);
}

extern "C" void kernel_launch(void* const* d_in, const int* in_sizes, int n_in,
                              void* d_out, int out_size, void* d_ws, size_t ws_size,
                              hipStream_t stream) {
    const float* x     = (const float*)d_in[0];
    const int*   edges = (const int*)d_in[1];
    const float* ea    = (const float*)d_in[2];
    const float* Wrel0 = (const float*)d_in[6],  *brel0 = (const float*)d_in[7],  *Wroot0 = (const float*)d_in[8];
    const float* Wrel1 = (const float*)d_in[9],  *brel1 = (const float*)d_in[10], *Wroot1 = (const float*)d_in[11];
    const float* Wrel2 = (const float*)d_in[12], *brel2 = (const float*)d_in[13], *Wroot2 = (const float*)d_in[14];
    const float* Wd0 = (const float*)d_in[15],  *bd0 = (const float*)d_in[16];
    const float* gnw0 = (const float*)d_in[17], *gnb0 = (const float*)d_in[18], *gnms0 = (const float*)d_in[19];
    const float* Wd1 = (const float*)d_in[20],  *bd1 = (const float*)d_in[21];
    const float* gnw1 = (const float*)d_in[22], *gnb1 = (const float*)d_in[23], *gnms1 = (const float*)d_in[24];
    const float* Wout = (const float*)d_in[25], *bout = (const float*)d_in[26];
    float* o = (float*)d_out;
    float* w = (float*)d_ws;

    float* x1  = w;
    float* x2  = x1 + 1600000;
    float* x3  = x2 + 3200000;
    float* agg = x3 + 6400000;
    float* P   = agg + 3200000;
    float* Qb  = P + 6400000;
    float* S0  = Qb + 6400000;
    float* Q0s = S0 + 12800;
    float* W1k = Q0s + 12800;        // reused: W1b bf16 packed (409600 u32)
    float* gam = W1k + 819200;
    float* S1  = gam + 6400;
    float* Q1s = S1 + 6400;
    float* ug  = Q1s + 6400;
    float* cg  = ug + 6400;
    float* vals = cg + 100;
    unsigned* W1b = (unsigned*)W1k;

    // ---- 3 GCN layers (LDS scatter, no global atomics / memsets) ----
    k_scatter2<5, 5><<<N_G, 256, 0, stream>>>(edges, ea, x, agg);
    k_dense<5, 32, 8><<<(N_NODES + 63) / 64, 256, 0, stream>>>(x, agg, Wrel0, brel0, Wroot0, x1);

    k_scatter2<32, 32><<<N_G, 256, 0, stream>>>(edges, ea, x1, agg);
    k_dense<32, 64, 8><<<(N_NODES + 31) / 32, 256, 0, stream>>>(x1, agg, Wrel1, brel1, Wroot1, x2);

    k_scatter2<64, 32><<<N_G * 2, 256, 0, stream>>>(edges, ea, x2, agg);
    k_dense<64, 128, 8><<<(N_NODES + 15) / 16, 256, 0, stream>>>(x2, agg, Wrel2, brel2, Wroot2, x3);

    // ---- P/Q decomposition (bd0 folded into P) ----
    k_affine128<16><<<(N_NODES + 31) / 32, 256, 0, stream>>>(x3, Wd0, bd0, P);
    k_affine128<16><<<(N_NODES + 31) / 32, 256, 0, stream>>>(x3, Wd0 + 129 * 128, nullptr, Qb);

    // ---- gnorm0 stats + fold into bf16 frag-packed W1b ----
    hipMemsetAsync(S0, 0, 25600 * sizeof(float), stream);
    k_h0s<<<N_G * 8, 256, 0, stream>>>(edges, ea, P, Qb, Wd0, S0, Q0s);
    k_fin0<<<N_G, 256, 0, stream>>>(S0, Q0s, gnw0, gnb0, gnms0, Wd1, bd1, W1b, gam);

    // ---- h1 stats pass (MFMA), fold gnorm1, final vals pass (MFMA) ----
    hipMemsetAsync(S1, 0, 12800 * sizeof(float), stream);
    k_h1m<0><<<N_G * 8, 256, 0, stream>>>(edges, ea, P, Qb, Wd0, W1b, gam,
                                          ug, cg, S1, Q1s, vals, o);
    k_fin1<<<N_G, 64, 0, stream>>>(S1, Q1s, gnw1, gnb1, gnms1, Wout, bout, ug, cg);
    k_h1m<1><<<N_G * 8, 256, 0, stream>>>(edges, ea, P, Qb, Wd0, W1b, gam,
                                          ug, cg, S1, Q1s, vals, o);

    // ---- per-graph softmax ----
    k_softmax<<<N_G, 256, 0, stream>>>(vals, o);
}

// Round 4
// 613.033 us; speedup vs baseline: 2.6294x; 1.4522x over previous
//
#include <hip/hip_runtime.h>

// GraphNN: 3 weighted-scatter GCN layers -> edge MLP decomposed via P/Q node
// GEMMs -> gnorm folded affine -> MFMA edge GEMM -> pair min/argmin -> softmax.
// R4: node GEMMs (x3, P/Q) now bf16 MFMA with hi/lo split (fp32-faithful).

#define N_NODES 50000
#define N_EDGES 400000
#define N_PAIRS 200000
#define N_G     100
#define EPG     4000
#define PPG     2000
#define NCHUNK  3125   // 50000/16

typedef float  f4   __attribute__((ext_vector_type(4)));
typedef short  bf8  __attribute__((ext_vector_type(8)));
typedef unsigned u32x4 __attribute__((ext_vector_type(4)));
typedef unsigned short ushort_t;

__device__ __forceinline__ float tanh_fast(float x) {
    float cx = fminf(15.f, fmaxf(-15.f, x));
    float e = __expf(2.f * cx);
    return (e - 1.f) * __builtin_amdgcn_rcpf(e + 1.f);
}
__device__ __forceinline__ unsigned f2bf(float f) {   // RNE fp32->bf16
    unsigned u = __float_as_uint(f);
    return (u + 0x7FFFu + ((u >> 16) & 1u)) >> 16;
}
__device__ __forceinline__ float bf2f(unsigned h) { return __uint_as_float(h << 16); }

// ---------------- GNN scatter via per-graph LDS (fp32 agg out) ---------------
template<int DIN, int FCH>
__global__ __launch_bounds__(256) void k_scatter2(
    const int* __restrict__ edges, const float* __restrict__ ea,
    const float* __restrict__ xin, float* __restrict__ agg) {
    __shared__ float s[500 * FCH];
    constexpr int NB = DIN / FCH;
    int g = blockIdx.x / NB, fc = blockIdx.x % NB, f0 = fc * FCH;
    for (int i = threadIdx.x; i < 500 * FCH; i += 256) s[i] = 0.f;
    __syncthreads();
    int p0 = g * PPG;
    for (int i = threadIdx.x; i < PPG * FCH; i += 256) {
        int p = p0 + i / FCH, f = i % FCH;
        int e = 2 * p;
        int sn = edges[e], dn = edges[N_EDGES + e];
        float wv = ea[2 * e] + ea[2 * e + 2];
        atomicAdd(&s[(dn - g * 500) * FCH + f], xin[sn * DIN + f0 + f] * wv);
    }
    __syncthreads();
    for (int i = threadIdx.x; i < 500 * FCH; i += 256) {
        int n = i / FCH, f = i % FCH;
        agg[(g * 500 + n) * DIN + f0 + f] = s[i];
    }
}

// ---- scatter variant writing hi/lo bf16 planes into cat cols [f0..f0+31] ----
__global__ __launch_bounds__(256) void k_scatter2cat(
    const int* __restrict__ edges, const float* __restrict__ ea,
    const float* __restrict__ xin, ushort_t* __restrict__ ch, ushort_t* __restrict__ cl) {
    __shared__ float s[500 * 32];
    int g = blockIdx.x >> 1, f0 = (blockIdx.x & 1) * 32;
    for (int i = threadIdx.x; i < 500 * 32; i += 256) s[i] = 0.f;
    __syncthreads();
    int p0 = g * PPG;
    for (int i = threadIdx.x; i < PPG * 32; i += 256) {
        int p = p0 + i / 32, f = i % 32;
        int e = 2 * p;
        int sn = edges[e], dn = edges[N_EDGES + e];
        float wv = ea[2 * e] + ea[2 * e + 2];
        atomicAdd(&s[(dn - g * 500) * 32 + f], xin[sn * 64 + f0 + f] * wv);
    }
    __syncthreads();
    for (int i = threadIdx.x; i < 500 * 32; i += 256) {
        int n = i / 32, f = i % 32;
        float v = s[i];
        unsigned hi = f2bf(v);
        size_t o = (size_t)(g * 500 + n) * 128 + f0 + f;
        ch[o] = (ushort_t)hi;
        cl[o] = (ushort_t)f2bf(v - bf2f(hi));
    }
}

// ---------------- dense: xout = tanh(agg@Wrel + brel + xin@Wroot) -------------
// optional: also write hi/lo bf16 into cat cols [64..64+DOUT)
template<int DIN, int DOUT, int NITER>
__global__ __launch_bounds__(256) void k_dense(
    const float* __restrict__ xin, const float* __restrict__ agg,
    const float* __restrict__ Wrel, const float* __restrict__ brel,
    const float* __restrict__ Wroot, float* __restrict__ xout,
    ushort_t* __restrict__ ch, ushort_t* __restrict__ cl) {
    __shared__ float wr[DIN * DOUT], wt[DIN * DOUT], bb[DOUT];
    constexpr int NPI = 256 / DOUT;
    __shared__ float sa[NPI][DIN], sx[NPI][DIN];
    for (int i = threadIdx.x; i < DIN * DOUT; i += 256) { wr[i] = Wrel[i]; wt[i] = Wroot[i]; }
    if (threadIdx.x < DOUT) bb[threadIdx.x] = brel[threadIdx.x];
    int j = threadIdx.x % DOUT;
    int nl = threadIdx.x / DOUT;
    for (int it = 0; it < NITER; ++it) {
        int nb = (blockIdx.x * NITER + it) * NPI;
        __syncthreads();
        for (int i = threadIdx.x; i < NPI * DIN; i += 256) {
            int nn = nb + i / DIN; int kk = i % DIN;
            float av = 0.f, xv = 0.f;
            if (nn < N_NODES) { av = agg[nn * DIN + kk]; xv = xin[nn * DIN + kk]; }
            sa[i / DIN][kk] = av; sx[i / DIN][kk] = xv;
        }
        __syncthreads();
        int n = nb + nl;
        if (n < N_NODES) {
            float acc = bb[j];
            #pragma unroll
            for (int k = 0; k < DIN; ++k)
                acc += sa[nl][k] * wr[k * DOUT + j] + sx[nl][k] * wt[k * DOUT + j];
            float v = tanhf(acc);
            xout[n * DOUT + j] = v;
            if (ch) {
                unsigned hi = f2bf(v);
                size_t o = (size_t)n * 128 + 64 + j;
                ch[o] = (ushort_t)hi;
                cl[o] = (ushort_t)f2bf(v - bf2f(hi));
            }
        }
    }
}

// ---------------- weight frag packers (R3-verified layout) --------------------
// word i: t=i&3, l=(i>>2)&63, kk=(i>>8)&3, n=i>>10; k=kk*32+((l>>4)<<3)+2t;
// j=16n+(l&15); dst[i] = bf(W[k][j]) | bf(W[k+1][j])<<16
__global__ void k_packWc(const float* __restrict__ Wrel2, const float* __restrict__ Wroot2,
                         unsigned* __restrict__ dst) {
    int i = blockIdx.x * 256 + threadIdx.x;   // 8192
    int t = i & 3, l = (i >> 2) & 63, kk = (i >> 8) & 3, n = i >> 10;
    int k = kk * 32 + ((l >> 4) << 3) + 2 * t;
    int j = 16 * n + (l & 15);
    float v0 = (k < 64) ? Wrel2[k * 128 + j] : Wroot2[(k - 64) * 128 + j];
    float v1 = (k + 1 < 64) ? Wrel2[(k + 1) * 128 + j] : Wroot2[(k + 1 - 64) * 128 + j];
    dst[i] = f2bf(v0) | (f2bf(v1) << 16);
}
__global__ void k_packWpq(const float* __restrict__ Wd0, unsigned* __restrict__ dst) {
    int i = blockIdx.x * 256 + threadIdx.x;   // 16384
    int t = i & 3, l = (i >> 2) & 63, kk = (i >> 8) & 3, n = i >> 10;
    int k = kk * 32 + ((l >> 4) << 3) + 2 * t;
    int j = 16 * n + (l & 15);
    float v0 = (j < 128) ? Wd0[k * 128 + j] : Wd0[(129 + k) * 128 + (j - 128)];
    float v1 = (j < 128) ? Wd0[(k + 1) * 128 + j] : Wd0[(129 + k + 1) * 128 + (j - 128)];
    dst[i] = f2bf(v0) | (f2bf(v1) << 16);
}

// ---------------- G1: x3 = tanh(cat @ Wc + brel2), hi/lo bf16 out -------------
// block 256 = 4 waves: colgroup = wave&1 (64 cols), mgroup = wave>>1.
__global__ __launch_bounds__(256) void k_g1(
    const ushort_t* __restrict__ Ah, const ushort_t* __restrict__ Al,
    const unsigned* __restrict__ Wb_, const float* __restrict__ bias,
    ushort_t* __restrict__ Oh, ushort_t* __restrict__ Ol) {
    int wave = threadIdx.x >> 6, lane = threadIdx.x & 63;
    int cg = wave & 1, mg = wave >> 1;
    int rl = lane & 15, gp = lane >> 4;
    u32x4 B[4][4];
    const u32x4* Wb = (const u32x4*)Wb_;
    #pragma unroll
    for (int n = 0; n < 4; ++n)
        #pragma unroll
        for (int kk = 0; kk < 4; ++kk)
            B[n][kk] = Wb[((cg * 4 + n) * 4 + kk) * 64 + lane];
    float bs[4];
    #pragma unroll
    for (int n = 0; n < 4; ++n) bs[n] = bias[cg * 64 + n * 16 + rl];
    for (int it = 0; it < 2; ++it) {
        int cid = (blockIdx.x * 2 + it) * 2 + mg;
        if (cid >= NCHUNK) continue;
        const u32x4* ph = (const u32x4*)(Ah + (size_t)(cid * 16 + rl) * 128 + gp * 8);
        const u32x4* pl = (const u32x4*)(Al + (size_t)(cid * 16 + rl) * 128 + gp * 8);
        bf8 ah[4], al4[4];
        #pragma unroll
        for (int kk = 0; kk < 4; ++kk) {
            ah[kk]  = __builtin_bit_cast(bf8, ph[kk * 4]);
            al4[kk] = __builtin_bit_cast(bf8, pl[kk * 4]);
        }
        f4 acc[4];
        #pragma unroll
        for (int n = 0; n < 4; ++n) acc[n] = (f4)0.f;
        #pragma unroll
        for (int kk = 0; kk < 4; ++kk) {
            #pragma unroll
            for (int n = 0; n < 4; ++n)
                acc[n] = __builtin_amdgcn_mfma_f32_16x16x32_bf16(
                    ah[kk], __builtin_bit_cast(bf8, B[n][kk]), acc[n], 0, 0, 0);
            #pragma unroll
            for (int n = 0; n < 4; ++n)
                acc[n] = __builtin_amdgcn_mfma_f32_16x16x32_bf16(
                    al4[kk], __builtin_bit_cast(bf8, B[n][kk]), acc[n], 0, 0, 0);
        }
        #pragma unroll
        for (int n = 0; n < 4; ++n)
            #pragma unroll
            for (int t = 0; t < 4; ++t) {
                float v = tanh_fast(acc[n][t] + bs[n]);
                unsigned hi = f2bf(v);
                int node = cid * 16 + gp * 4 + t;
                int col = cg * 64 + n * 16 + rl;
                Oh[(size_t)node * 128 + col] = (ushort_t)hi;
                Ol[(size_t)node * 128 + col] = (ushort_t)f2bf(v - bf2f(hi));
            }
    }
}

// ---------------- G2: [P|Q] = x3 @ Wpq (+bd0 on P cols), fp32 out -------------
// block 256 = 4 waves, each wave = one 64-col group of 256.
__global__ __launch_bounds__(256) void k_g2(
    const ushort_t* __restrict__ Ah, const ushort_t* __restrict__ Al,
    const unsigned* __restrict__ Wb_, const float* __restrict__ bd0,
    float* __restrict__ P, float* __restrict__ Qb) {
    int cg = threadIdx.x >> 6, lane = threadIdx.x & 63;
    int rl = lane & 15, gp = lane >> 4;
    u32x4 B[4][4];
    const u32x4* Wb = (const u32x4*)Wb_;
    #pragma unroll
    for (int n = 0; n < 4; ++n)
        #pragma unroll
        for (int kk = 0; kk < 4; ++kk)
            B[n][kk] = Wb[((cg * 4 + n) * 4 + kk) * 64 + lane];
    float bs[4];
    #pragma unroll
    for (int n = 0; n < 4; ++n) {
        int j = cg * 64 + n * 16 + rl;
        bs[n] = (j < 128) ? bd0[j] : 0.f;
    }
    for (int it = 0; it < 2; ++it) {
        int cid = blockIdx.x * 2 + it;
        if (cid >= NCHUNK) continue;
        const u32x4* ph = (const u32x4*)(Ah + (size_t)(cid * 16 + rl) * 128 + gp * 8);
        const u32x4* pl = (const u32x4*)(Al + (size_t)(cid * 16 + rl) * 128 + gp * 8);
        bf8 ah[4], al4[4];
        #pragma unroll
        for (int kk = 0; kk < 4; ++kk) {
            ah[kk]  = __builtin_bit_cast(bf8, ph[kk * 4]);
            al4[kk] = __builtin_bit_cast(bf8, pl[kk * 4]);
        }
        f4 acc[4];
        #pragma unroll
        for (int n = 0; n < 4; ++n) acc[n] = (f4)0.f;
        #pragma unroll
        for (int kk = 0; kk < 4; ++kk) {
            #pragma unroll
            for (int n = 0; n < 4; ++n)
                acc[n] = __builtin_amdgcn_mfma_f32_16x16x32_bf16(
                    ah[kk], __builtin_bit_cast(bf8, B[n][kk]), acc[n], 0, 0, 0);
            #pragma unroll
            for (int n = 0; n < 4; ++n)
                acc[n] = __builtin_amdgcn_mfma_f32_16x16x32_bf16(
                    al4[kk], __builtin_bit_cast(bf8, B[n][kk]), acc[n], 0, 0, 0);
        }
        #pragma unroll
        for (int n = 0; n < 4; ++n) {
            int j = cg * 64 + n * 16 + rl;
            #pragma unroll
            for (int t = 0; t < 4; ++t) {
                float v = acc[n][t] + bs[n];
                int node = cid * 16 + gp * 4 + t;
                if (j < 128) P[(size_t)node * 128 + j] = v;
                else         Qb[(size_t)node * 128 + (j - 128)] = v;
            }
        }
    }
}

// ---------------- h0 stats: per-graph sum/sumsq of tanh(P[s]+Q[d]+w*wm) ------
__global__ __launch_bounds__(256, 1) void k_h0s(
    const int* __restrict__ edges, const float* __restrict__ ea,
    const float* __restrict__ P, const float* __restrict__ Qb,
    const float* __restrict__ Wd0,
    float* __restrict__ S0, float* __restrict__ Q0s) {
    int g = blockIdx.x >> 3, tb = blockIdx.x & 7;
    int wave = threadIdx.x >> 6, lane = threadIdx.x & 63;
    int row = lane & 15, grp = lane >> 4;
    int slot = tb * 4 + wave;
    f4 wmr[4][2];
    #pragma unroll
    for (int kk = 0; kk < 4; ++kk) {
        const f4* wmp = (const f4*)(Wd0 + 16384 + kk * 32 + grp * 8);
        wmr[kk][0] = wmp[0]; wmr[kk][1] = wmp[1];
    }
    f4 s[4][2], q[4][2];
    #pragma unroll
    for (int kk = 0; kk < 4; ++kk)
        #pragma unroll
        for (int h = 0; h < 2; ++h) { s[kk][h] = (f4)0.f; q[kk][h] = (f4)0.f; }

    for (int j = 0; j < 4; ++j) {
        int tile = slot + 32 * j;
        if (tile >= 125) break;
        int eg0 = g * EPG + tile * 32;
        #pragma unroll
        for (int m = 0; m < 2; ++m) {
            int e = eg0 + 16 * m + row;
            int sn = edges[e], dn = edges[N_EDGES + e];
            float w = ea[2 * e];
            const f4* Pr = (const f4*)(P + sn * 128);
            const f4* Qr = (const f4*)(Qb + dn * 128);
            #pragma unroll
            for (int kk = 0; kk < 4; ++kk) {
                int o = kk * 8 + grp * 2;
                f4 p0 = Pr[o], p1 = Pr[o + 1];
                f4 q0 = Qr[o], q1 = Qr[o + 1];
                #pragma unroll
                for (int r = 0; r < 4; ++r) {
                    float h0 = tanh_fast(p0[r] + q0[r] + w * wmr[kk][0][r]);
                    float h1 = tanh_fast(p1[r] + q1[r] + w * wmr[kk][1][r]);
                    s[kk][0][r] += h0; q[kk][0][r] += h0 * h0;
                    s[kk][1][r] += h1; q[kk][1][r] += h1 * h1;
                }
            }
        }
    }
    #pragma unroll
    for (int kk = 0; kk < 4; ++kk)
        #pragma unroll
        for (int h = 0; h < 2; ++h)
            #pragma unroll
            for (int r = 0; r < 4; ++r) {
                float sv = s[kk][h][r], qv = q[kk][h][r];
                sv += __shfl_xor(sv, 1); sv += __shfl_xor(sv, 2);
                sv += __shfl_xor(sv, 4); sv += __shfl_xor(sv, 8);
                qv += __shfl_xor(qv, 1); qv += __shfl_xor(qv, 2);
                qv += __shfl_xor(qv, 4); qv += __shfl_xor(qv, 8);
                if (row == 0) {
                    int k = kk * 32 + grp * 8 + h * 4 + r;
                    atomicAdd(&S0[g * 128 + k], sv);
                    atomicAdd(&Q0s[g * 128 + k], qv);
                }
            }
}

// ---------------- fold gnorm0 into Wd1 -> bf16 frag-packed W1b + gam ---------
__global__ __launch_bounds__(256) void k_fin0(
    const float* __restrict__ S0, const float* __restrict__ Q0s,
    const float* __restrict__ gnw, const float* __restrict__ gnb, const float* __restrict__ gnms,
    const float* __restrict__ Wd1, const float* __restrict__ bd1,
    unsigned* __restrict__ W1b, float* __restrict__ gam) {
    int g = blockIdx.x;
    __shared__ float al[128], be[128];
    if (threadIdx.x < 128) {
        int k = threadIdx.x;
        float S = S0[g * 128 + k], Q = Q0s[g * 128 + k];
        float mean = S * (1.f / EPG);
        float t = mean * gnms[k];
        float var = (Q - 2.f * t * S) * (1.f / EPG) + t * t;
        float a = gnw[k] * rsqrtf(var + 1e-5f);
        al[k] = a;
        be[k] = gnb[k] - a * t;
    }
    __syncthreads();
    unsigned* Wb = W1b + (size_t)g * 4096;
    for (int i = threadIdx.x; i < 4096; i += 256) {
        int t = i & 3, l = (i >> 2) & 63, kk = (i >> 8) & 3, n = i >> 10;
        int k = kk * 32 + ((l >> 4) << 3) + 2 * t;
        int j = 16 * n + (l & 15);
        unsigned lo = f2bf(al[k] * Wd1[k * 64 + j]);
        unsigned hi = f2bf(al[k + 1] * Wd1[(k + 1) * 64 + j]);
        Wb[i] = lo | (hi << 16);
    }
    if (threadIdx.x < 64) {
        int j = threadIdx.x;
        float acc = bd1[j];
        #pragma unroll 8
        for (int k = 0; k < 128; ++k) acc += be[k] * Wd1[k * 64 + j];
        gam[g * 64 + j] = acc;
    }
}

// ---------------- MFMA h1 pass: stats (DO_VALS=0) or final vals (=1) ---------
template<int DO_VALS>
__global__ __launch_bounds__(256, 1) void k_h1m(
    const int* __restrict__ edges, const float* __restrict__ ea,
    const float* __restrict__ P, const float* __restrict__ Qb,
    const float* __restrict__ Wd0,
    const unsigned* __restrict__ W1b, const float* __restrict__ gam,
    const float* __restrict__ ug, const float* __restrict__ cg,
    float* __restrict__ S1, float* __restrict__ Q1s,
    float* __restrict__ vals, float* __restrict__ outp) {
    int g = blockIdx.x >> 3, tb = blockIdx.x & 7;
    int wave = threadIdx.x >> 6, lane = threadIdx.x & 63;
    int col = lane & 15, grp = lane >> 4;
    int slot = tb * 4 + wave;

    bf8 bf[4][4];
    {
        const u32x4* Wb = (const u32x4*)(W1b + (size_t)g * 4096);
        #pragma unroll
        for (int n = 0; n < 4; ++n)
            #pragma unroll
            for (int kk = 0; kk < 4; ++kk)
                bf[n][kk] = __builtin_bit_cast(bf8, Wb[(n * 4 + kk) * 64 + lane]);
    }
    f4 wmr[4][2];
    #pragma unroll
    for (int kk = 0; kk < 4; ++kk) {
        const f4* wmp = (const f4*)(Wd0 + 16384 + kk * 32 + grp * 8);
        wmr[kk][0] = wmp[0]; wmr[kk][1] = wmp[1];
    }
    float gamn[4], un[4] = {0.f, 0.f, 0.f, 0.f};
    #pragma unroll
    for (int n = 0; n < 4; ++n) gamn[n] = gam[g * 64 + 16 * n + col];
    float cgv = 0.f;
    if (DO_VALS) {
        #pragma unroll
        for (int n = 0; n < 4; ++n) un[n] = ug[g * 64 + 16 * n + col];
        cgv = cg[g];
    }
    float sacc[4] = {0.f, 0.f, 0.f, 0.f}, qacc[4] = {0.f, 0.f, 0.f, 0.f};

    for (int j = 0; j < 4; ++j) {
        int tile = slot + 32 * j;
        if (tile >= 125) break;
        int eg0 = g * EPG + tile * 32;
        bf8 af[2][4];
        #pragma unroll
        for (int m = 0; m < 2; ++m) {
            int e = eg0 + 16 * m + col;
            int sn = edges[e], dn = edges[N_EDGES + e];
            float w = ea[2 * e];
            const f4* Pr = (const f4*)(P + sn * 128);
            const f4* Qr = (const f4*)(Qb + dn * 128);
            #pragma unroll
            for (int kk = 0; kk < 4; ++kk) {
                int o = kk * 8 + grp * 2;
                f4 p0 = Pr[o], p1 = Pr[o + 1];
                f4 q0 = Qr[o], q1 = Qr[o + 1];
                bf8 a;
                #pragma unroll
                for (int r = 0; r < 4; ++r) {
                    float h0 = tanh_fast(p0[r] + q0[r] + w * wmr[kk][0][r]);
                    float h1 = tanh_fast(p1[r] + q1[r] + w * wmr[kk][1][r]);
                    a[r]     = (short)f2bf(h0);
                    a[4 + r] = (short)f2bf(h1);
                }
                af[m][kk] = a;
            }
        }
        f4 acc[2][4];
        #pragma unroll
        for (int m = 0; m < 2; ++m)
            #pragma unroll
            for (int n = 0; n < 4; ++n) acc[m][n] = (f4)0.f;
        #pragma unroll
        for (int kk = 0; kk < 4; ++kk)
            #pragma unroll
            for (int m = 0; m < 2; ++m)
                #pragma unroll
                for (int n = 0; n < 4; ++n)
                    acc[m][n] = __builtin_amdgcn_mfma_f32_16x16x32_bf16(
                        af[m][kk], bf[n][kk], acc[m][n], 0, 0, 0);

        if (DO_VALS) {
            float rp[2][4];
            #pragma unroll
            for (int m = 0; m < 2; ++m)
                #pragma unroll
                for (int t = 0; t < 4; ++t) {
                    float v = 0.f;
                    #pragma unroll
                    for (int n = 0; n < 4; ++n)
                        v += un[n] * tanh_fast(acc[m][n][t] + gamn[n]);
                    v += __shfl_xor(v, 1); v += __shfl_xor(v, 2);
                    v += __shfl_xor(v, 4); v += __shfl_xor(v, 8);
                    rp[m][t] = v + cgv;
                }
            if (col == 0) {
                #pragma unroll
                for (int m = 0; m < 2; ++m)
                    #pragma unroll
                    for (int pr = 0; pr < 2; ++pr) {
                        float va = rp[m][2 * pr], vb = rp[m][2 * pr + 1];
                        int p = ((eg0 + 16 * m + grp * 4) >> 1) + pr;
                        vals[p] = fminf(va, vb);
                        outp[600000 + p] = (vb < va) ? 1.f : 0.f;
                        int e = 2 * p;
                        outp[p]          = (float)edges[e];
                        outp[200000 + p] = (float)edges[N_EDGES + e];
                    }
            }
        } else {
            #pragma unroll
            for (int m = 0; m < 2; ++m)
                #pragma unroll
                for (int n = 0; n < 4; ++n)
                    #pragma unroll
                    for (int t = 0; t < 4; ++t) {
                        float h = tanh_fast(acc[m][n][t] + gamn[n]);
                        sacc[n] += h; qacc[n] += h * h;
                    }
        }
    }
    if (!DO_VALS) {
        #pragma unroll
        for (int n = 0; n < 4; ++n) {
            float s = sacc[n], q = qacc[n];
            s += __shfl_xor(s, 16); s += __shfl_xor(s, 32);
            q += __shfl_xor(q, 16); q += __shfl_xor(q, 32);
            if (lane < 16) {
                atomicAdd(&S1[g * 64 + 16 * n + col], s);
                atomicAdd(&Q1s[g * 64 + 16 * n + col], q);
            }
        }
    }
}

// ---------------- fold gnorm1 into Wout ---------------------------------------
__global__ void k_fin1(const float* __restrict__ S1, const float* __restrict__ Q1s,
                       const float* __restrict__ gnw, const float* __restrict__ gnb,
                       const float* __restrict__ gnms,
                       const float* __restrict__ Wout, const float* __restrict__ bout,
                       float* __restrict__ ug, float* __restrict__ cg) {
    int g = blockIdx.x; int j = threadIdx.x;  // 64 threads
    float S = S1[g * 64 + j], Q = Q1s[g * 64 + j];
    float mean = S * (1.f / EPG);
    float t = mean * gnms[j];
    float var = (Q - 2.f * t * S) * (1.f / EPG) + t * t;
    float a = gnw[j] * rsqrtf(var + 1e-5f);
    float b = gnb[j] - a * t;
    ug[g * 64 + j] = a * Wout[j];
    float c = b * Wout[j];
    #pragma unroll
    for (int off = 32; off; off >>= 1) c += __shfl_xor(c, off);
    if (j == 0) cg[g] = c + bout[0];
}

// ---------------- per-graph softmax over pair-min vals ------------------------
__global__ __launch_bounds__(256) void k_softmax(const float* __restrict__ vals,
                                                 float* __restrict__ outp) {
    int g = blockIdx.x;
    __shared__ float rbuf[4], rbuf2[4];
    int t = threadIdx.x;
    const float* v = vals + g * PPG;
    float mx = -1e30f;
    for (int i = t; i < PPG; i += 256) mx = fmaxf(mx, v[i]);
    #pragma unroll
    for (int off = 32; off; off >>= 1) mx = fmaxf(mx, __shfl_xor(mx, off));
    if ((t & 63) == 0) rbuf[t >> 6] = mx;
    __syncthreads();
    mx = fmaxf(fmaxf(rbuf[0], rbuf[1]), fmaxf(rbuf[2], rbuf[3]));
    float sm = 0.f;
    for (int i = t; i < PPG; i += 256) sm += expf(v[i] - mx);
    #pragma unroll
    for (int off = 32; off; off >>= 1) sm += __shfl_xor(sm, off);
    if ((t & 63) == 0) rbuf2[t >> 6] = sm;
    __syncthreads();
    sm = rbuf2[0] + rbuf2[1] + rbuf2[2] + rbuf2[3];
    for (int i = t; i < PPG; i += 256)
        outp[400000 + g * PPG + i] = expf(v[i] - mx) / (sm + 1e-16f);
}

extern "C" void kernel_launch(void* const* d_in, const int* in_sizes, int n_in,
                              void* d_out, int out_size, void* d_ws, size_t ws_size,
                              hipStream_t stream) {
    const float* x     = (const float*)d_in[0];
    const int*   edges = (const int*)d_in[1];
    const float* ea    = (const float*)d_in[2];
    const float* Wrel0 = (const float*)d_in[6],  *brel0 = (const float*)d_in[7],  *Wroot0 = (const float*)d_in[8];
    const float* Wrel1 = (const float*)d_in[9],  *brel1 = (const float*)d_in[10], *Wroot1 = (const float*)d_in[11];
    const float* Wrel2 = (const float*)d_in[12], *brel2 = (const float*)d_in[13], *Wroot2 = (const float*)d_in[14];
    const float* Wd0 = (const float*)d_in[15],  *bd0 = (const float*)d_in[16];
    const float* gnw0 = (const float*)d_in[17], *gnb0 = (const float*)d_in[18], *gnms0 = (const float*)d_in[19];
    const float* Wd1 = (const float*)d_in[20],  *bd1 = (const float*)d_in[21];
    const float* gnw1 = (const float*)d_in[22], *gnb1 = (const float*)d_in[23], *gnms1 = (const float*)d_in[24];
    const float* Wout = (const float*)d_in[25], *bout = (const float*)d_in[26];
    float* o = (float*)d_out;
    float* w = (float*)d_ws;

    float* x1   = w;                       // 1.6M
    float* x2   = x1 + 1600000;            // 3.2M
    float* agg  = x2 + 3200000;            // 1.6M
    float* P    = agg + 1600000;           // 6.4M
    float* Qb   = P + 6400000;             // 6.4M
    ushort_t* cat_hi = (ushort_t*)(Qb + 6400000);        // 1.6M f-units
    ushort_t* cat_lo = (ushort_t*)(Qb + 6400000 + 1600000);
    ushort_t* x3_hi  = (ushort_t*)(Qb + 6400000 + 3200000);
    ushort_t* x3_lo  = (ushort_t*)(Qb + 6400000 + 4800000);
    float* after = Qb + 6400000 + 6400000;
    unsigned* Wcb  = (unsigned*)after;     // 8192
    unsigned* Wpqb = Wcb + 8192;           // 16384
    float* S0  = (float*)(Wpqb + 16384);   // 12800
    float* Q0s = S0 + 12800;               // 12800
    unsigned* W1b = (unsigned*)(Q0s + 12800);  // 409600
    float* gam = (float*)(W1b + 409600);   // 6400
    float* S1  = gam + 6400;
    float* Q1s = S1 + 6400;
    float* ug  = Q1s + 6400;
    float* cg  = ug + 6400;
    float* vals = cg + 100;                // 200000

    // ---- weight frag packing (no data deps) ----
    k_packWc<<<32, 256, 0, stream>>>(Wrel2, Wroot2, Wcb);
    k_packWpq<<<64, 256, 0, stream>>>(Wd0, Wpqb);

    // ---- 3 GCN layers ----
    k_scatter2<5, 5><<<N_G, 256, 0, stream>>>(edges, ea, x, agg);
    k_dense<5, 32, 8><<<(N_NODES + 63) / 64, 256, 0, stream>>>(x, agg, Wrel0, brel0, Wroot0, x1, nullptr, nullptr);

    k_scatter2<32, 32><<<N_G, 256, 0, stream>>>(edges, ea, x1, agg);
    k_dense<32, 64, 8><<<(N_NODES + 31) / 32, 256, 0, stream>>>(x1, agg, Wrel1, brel1, Wroot1, x2, cat_hi, cat_lo);

    k_scatter2cat<<<N_G * 2, 256, 0, stream>>>(edges, ea, x2, cat_hi, cat_lo);

    // ---- x3 (MFMA, hi/lo) then [P|Q] (MFMA) ----
    k_g1<<<(NCHUNK + 3) / 4, 256, 0, stream>>>(cat_hi, cat_lo, Wcb, brel2, x3_hi, x3_lo);
    k_g2<<<(NCHUNK + 1) / 2, 256, 0, stream>>>(x3_hi, x3_lo, Wpqb, bd0, P, Qb);

    // ---- gnorm0 stats + fold into bf16 frag-packed W1b ----
    hipMemsetAsync(S0, 0, 25600 * sizeof(float), stream);
    k_h0s<<<N_G * 8, 256, 0, stream>>>(edges, ea, P, Qb, Wd0, S0, Q0s);
    k_fin0<<<N_G, 256, 0, stream>>>(S0, Q0s, gnw0, gnb0, gnms0, Wd1, bd1, W1b, gam);

    // ---- h1 stats pass (MFMA), fold gnorm1, final vals pass (MFMA) ----
    hipMemsetAsync(S1, 0, 12800 * sizeof(float), stream);
    k_h1m<0><<<N_G * 8, 256, 0, stream>>>(edges, ea, P, Qb, Wd0, W1b, gam,
                                          ug, cg, S1, Q1s, vals, o);
    k_fin1<<<N_G, 64, 0, stream>>>(S1, Q1s, gnw1, gnb1, gnms1, Wout, bout, ug, cg);
    k_h1m<1><<<N_G * 8, 256, 0, stream>>>(edges, ea, P, Qb, Wd0, W1b, gam,
                                          ug, cg, S1, Q1s, vals, o);

    // ---- per-graph softmax ----
    k_softmax<<<N_G, 256, 0, stream>>>(vals, o);
}

// Round 5
// 447.350 us; speedup vs baseline: 3.6032x; 1.3704x over previous
//
#include <hip/hip_runtime.h>

// GraphNN R5: dst-CSR built on device -> gather (no atomics, big grids) for all
// 3 GCN aggregations; all GEMMs >=64-wide on MFMA (hi/lo bf16 split, fp32-faithful).
// Pipeline: CSR -> gath5 -> dense1(5->32) -> gath32 -> g1b(64->64 MFMA) ->
// gath64 -> g1(128->128 MFMA) -> g2(128->256 MFMA) -> h0 stats -> fold ->
// h1 MFMA stats -> fold -> h1 MFMA vals -> softmax.
//
// ws aliasing (float units), all alias pairs ordered-safe by liveness:
//  A:[0,8.25M): agg5|x1|x2|c2h|c2l  then x3h|x3l (originals dead before k_g1)
//  B:[8.25M,21.05M): cat planes (written g1b/gath64, read g1) then P|Qb (k_g2)
//  tail:[21.05M,~22.3M): packs, csr, stats, W1b, vals

#define N_NODES 50000
#define N_EDGES 400000
#define N_PAIRS 200000
#define N_G     100
#define EPG     4000
#define PPG     2000
#define NCHUNK  3125   // 50000/16

typedef float  f4   __attribute__((ext_vector_type(4)));
typedef short  bf8  __attribute__((ext_vector_type(8)));
typedef unsigned u32x4 __attribute__((ext_vector_type(4)));
typedef unsigned short ushort_t;

__device__ __forceinline__ float tanh_fast(float x) {
    float cx = fminf(15.f, fmaxf(-15.f, x));
    float e = __expf(2.f * cx);
    return (e - 1.f) * __builtin_amdgcn_rcpf(e + 1.f);
}
__device__ __forceinline__ unsigned f2bf(float f) {   // RNE fp32->bf16
    unsigned u = __float_as_uint(f);
    return (u + 0x7FFFu + ((u >> 16) & 1u)) >> 16;
}
__device__ __forceinline__ float bf2f(unsigned h) { return __uint_as_float(h << 16); }

// ---------------- CSR build: count / scan / fill ------------------------------
__global__ void k_csr_count(const int* __restrict__ edges, int* __restrict__ cnt) {
    int p = blockIdx.x * 256 + threadIdx.x;
    if (p >= N_PAIRS) return;
    atomicAdd(&cnt[edges[N_EDGES + 2 * p]], 1);
}
__global__ __launch_bounds__(512) void k_csr_scan(const int* __restrict__ cnt,
                                                  int* __restrict__ offs) {
    __shared__ int s[512];
    int g = blockIdx.x, t = threadIdx.x;
    int v = (t < 500) ? cnt[g * 500 + t] : 0;
    s[t] = v; __syncthreads();
    for (int off = 1; off < 512; off <<= 1) {
        int a = (t >= off) ? s[t - off] : 0;
        __syncthreads();
        s[t] += a; __syncthreads();
    }
    if (t < 500) offs[g * 500 + t] = g * PPG + s[t] - v;   // exclusive, global pos
}
__global__ void k_csr_fill(const int* __restrict__ edges, const float* __restrict__ ea,
                           const int* __restrict__ offs, int* __restrict__ fillc,
                           int* __restrict__ esrc, float* __restrict__ ew) {
    int p = blockIdx.x * 256 + threadIdx.x;
    if (p >= N_PAIRS) return;
    int d = edges[N_EDGES + 2 * p];
    int pos = offs[d] + atomicAdd(&fillc[d], 1);
    esrc[pos] = edges[2 * p];
    ew[pos] = ea[4 * p] + ea[4 * p + 2];     // two dup edges' weights
}

// ---------------- gathers (agg[n] = sum_{p in(n)} x[src_p]*w_p) ---------------
__global__ __launch_bounds__(256) void k_gath5(
    const int* __restrict__ cnt, const int* __restrict__ offs,
    const int* __restrict__ esrc, const float* __restrict__ ew,
    const float* __restrict__ x, float* __restrict__ agg) {
    int t = blockIdx.x * 256 + threadIdx.x;
    int n = t >> 3, k = t & 7;
    if (n >= N_NODES || k >= 5) return;
    int o0 = offs[n], c = cnt[n];
    float acc = 0.f;
    for (int i = o0; i < o0 + c; ++i) acc += x[esrc[i] * 5 + k] * ew[i];
    agg[n * 5 + k] = acc;
}
__global__ __launch_bounds__(256) void k_gath32(
    const int* __restrict__ cnt, const int* __restrict__ offs,
    const int* __restrict__ esrc, const float* __restrict__ ew,
    const float* __restrict__ x1, ushort_t* __restrict__ c2h, ushort_t* __restrict__ c2l) {
    int n = blockIdx.x * 8 + (threadIdx.x >> 5), k = threadIdx.x & 31;
    if (n >= N_NODES) return;
    int o0 = offs[n], c = cnt[n];
    float acc = 0.f;
    for (int i = o0; i < o0 + c; ++i) acc += x1[esrc[i] * 32 + k] * ew[i];
    unsigned hi = f2bf(acc);
    size_t o = (size_t)n * 64 + k;           // cat2 cols 0..31
    c2h[o] = (ushort_t)hi;
    c2l[o] = (ushort_t)f2bf(acc - bf2f(hi));
}
__global__ __launch_bounds__(256) void k_gath64(
    const int* __restrict__ cnt, const int* __restrict__ offs,
    const int* __restrict__ esrc, const float* __restrict__ ew,
    const float* __restrict__ x2, ushort_t* __restrict__ ch, ushort_t* __restrict__ cl) {
    int n = blockIdx.x * 4 + (threadIdx.x >> 6), k = threadIdx.x & 63;
    if (n >= N_NODES) return;
    int o0 = offs[n], c = cnt[n];
    float acc = 0.f;
    for (int i = o0; i < o0 + c; ++i) acc += x2[esrc[i] * 64 + k] * ew[i];
    unsigned hi = f2bf(acc);
    size_t o = (size_t)n * 128 + k;          // cat cols 0..63
    ch[o] = (ushort_t)hi;
    cl[o] = (ushort_t)f2bf(acc - bf2f(hi));
}

// ---------------- layer1 dense 5->32: x1 fp32 + cat2 cols 32..63 hi/lo --------
__global__ __launch_bounds__(256) void k_dense1(
    const float* __restrict__ x, const float* __restrict__ agg,
    const float* __restrict__ Wrel, const float* __restrict__ brel,
    const float* __restrict__ Wroot, float* __restrict__ x1,
    ushort_t* __restrict__ c2h, ushort_t* __restrict__ c2l) {
    __shared__ float wr[160], wt[160], bb[32];
    __shared__ float sa[8][5], sx[8][5];
    for (int i = threadIdx.x; i < 160; i += 256) { wr[i] = Wrel[i]; wt[i] = Wroot[i]; }
    if (threadIdx.x < 32) bb[threadIdx.x] = brel[threadIdx.x];
    int j = threadIdx.x & 31, nl = threadIdx.x >> 5;
    int nb = blockIdx.x * 8;
    __syncthreads();
    for (int i = threadIdx.x; i < 40; i += 256) {
        int nn = nb + i / 5, kk = i % 5;
        float av = 0.f, xv = 0.f;
        if (nn < N_NODES) { av = agg[nn * 5 + kk]; xv = x[nn * 5 + kk]; }
        sa[i / 5][kk] = av; sx[i / 5][kk] = xv;
    }
    __syncthreads();
    int n = nb + nl;
    if (n < N_NODES) {
        float acc = bb[j];
        #pragma unroll
        for (int k = 0; k < 5; ++k)
            acc += sa[nl][k] * wr[k * 32 + j] + sx[nl][k] * wt[k * 32 + j];
        float v = tanhf(acc);
        x1[n * 32 + j] = v;
        unsigned hi = f2bf(v);
        size_t o = (size_t)n * 64 + 32 + j;  // cat2 cols 32..63
        c2h[o] = (ushort_t)hi;
        c2l[o] = (ushort_t)f2bf(v - bf2f(hi));
    }
}

// ---------------- weight frag packers (R3-verified layout) --------------------
__global__ void k_packWc(const float* __restrict__ Wrel2, const float* __restrict__ Wroot2,
                         unsigned* __restrict__ dst) {
    int i = blockIdx.x * 256 + threadIdx.x;   // 8192
    int t = i & 3, l = (i >> 2) & 63, kk = (i >> 8) & 3, n = i >> 10;
    int k = kk * 32 + ((l >> 4) << 3) + 2 * t;
    int j = 16 * n + (l & 15);
    float v0 = (k < 64) ? Wrel2[k * 128 + j] : Wroot2[(k - 64) * 128 + j];
    float v1 = (k + 1 < 64) ? Wrel2[(k + 1) * 128 + j] : Wroot2[(k + 1 - 64) * 128 + j];
    dst[i] = f2bf(v0) | (f2bf(v1) << 16);
}
__global__ void k_packWpq(const float* __restrict__ Wd0, unsigned* __restrict__ dst) {
    int i = blockIdx.x * 256 + threadIdx.x;   // 16384
    int t = i & 3, l = (i >> 2) & 63, kk = (i >> 8) & 3, n = i >> 10;
    int k = kk * 32 + ((l >> 4) << 3) + 2 * t;
    int j = 16 * n + (l & 15);
    float v0 = (j < 128) ? Wd0[k * 128 + j] : Wd0[(129 + k) * 128 + (j - 128)];
    float v1 = (j < 128) ? Wd0[(k + 1) * 128 + j] : Wd0[(129 + k + 1) * 128 + (j - 128)];
    dst[i] = f2bf(v0) | (f2bf(v1) << 16);
}
__global__ void k_packW2(const float* __restrict__ Wrel1, const float* __restrict__ Wroot1,
                         unsigned* __restrict__ dst) {
    int i = blockIdx.x * 256 + threadIdx.x;   // 2048
    int t = i & 3, l = (i >> 2) & 63, kk = (i >> 8) & 1, n = i >> 9;
    int k = kk * 32 + ((l >> 4) << 3) + 2 * t;
    int j = 16 * n + (l & 15);
    float v0 = (k < 32) ? Wrel1[k * 64 + j] : Wroot1[(k - 32) * 64 + j];
    float v1 = (k + 1 < 32) ? Wrel1[(k + 1) * 64 + j] : Wroot1[(k + 1 - 32) * 64 + j];
    dst[i] = f2bf(v0) | (f2bf(v1) << 16);
}

// ---------------- G1b: x2 = tanh(cat2 @ W2 + brel1), 64->64 MFMA --------------
__global__ __launch_bounds__(256) void k_g1b(
    const ushort_t* __restrict__ Ah, const ushort_t* __restrict__ Al,
    const unsigned* __restrict__ Wb_, const float* __restrict__ bias,
    float* __restrict__ x2, ushort_t* __restrict__ ch, ushort_t* __restrict__ cl) {
    int wave = threadIdx.x >> 6, lane = threadIdx.x & 63;
    int rl = lane & 15, gp = lane >> 4;
    int cid = blockIdx.x * 4 + wave;
    if (cid >= NCHUNK) return;
    u32x4 B[4][2];
    const u32x4* Wb = (const u32x4*)Wb_;
    #pragma unroll
    for (int n = 0; n < 4; ++n)
        #pragma unroll
        for (int kk = 0; kk < 2; ++kk)
            B[n][kk] = Wb[(n * 2 + kk) * 64 + lane];
    float bs[4];
    #pragma unroll
    for (int n = 0; n < 4; ++n) bs[n] = bias[n * 16 + rl];
    const u32x4* ph = (const u32x4*)(Ah + (size_t)(cid * 16 + rl) * 64 + gp * 8);
    const u32x4* pl = (const u32x4*)(Al + (size_t)(cid * 16 + rl) * 64 + gp * 8);
    bf8 ah[2], al4[2];
    #pragma unroll
    for (int kk = 0; kk < 2; ++kk) {
        ah[kk]  = __builtin_bit_cast(bf8, ph[kk * 4]);
        al4[kk] = __builtin_bit_cast(bf8, pl[kk * 4]);
    }
    f4 acc[4];
    #pragma unroll
    for (int n = 0; n < 4; ++n) acc[n] = (f4)0.f;
    #pragma unroll
    for (int kk = 0; kk < 2; ++kk) {
        #pragma unroll
        for (int n = 0; n < 4; ++n)
            acc[n] = __builtin_amdgcn_mfma_f32_16x16x32_bf16(
                ah[kk], __builtin_bit_cast(bf8, B[n][kk]), acc[n], 0, 0, 0);
        #pragma unroll
        for (int n = 0; n < 4; ++n)
            acc[n] = __builtin_amdgcn_mfma_f32_16x16x32_bf16(
                al4[kk], __builtin_bit_cast(bf8, B[n][kk]), acc[n], 0, 0, 0);
    }
    #pragma unroll
    for (int n = 0; n < 4; ++n)
        #pragma unroll
        for (int t = 0; t < 4; ++t) {
            float v = tanh_fast(acc[n][t] + bs[n]);
            int node = cid * 16 + gp * 4 + t;
            int col = n * 16 + rl;
            x2[(size_t)node * 64 + col] = v;
            unsigned hi = f2bf(v);
            size_t o = (size_t)node * 128 + 64 + col;   // cat cols 64..127
            ch[o] = (ushort_t)hi;
            cl[o] = (ushort_t)f2bf(v - bf2f(hi));
        }
}

// ---------------- G1: x3 = tanh(cat @ Wc + brel2), hi/lo bf16 out -------------
__global__ __launch_bounds__(256) void k_g1(
    const ushort_t* __restrict__ Ah, const ushort_t* __restrict__ Al,
    const unsigned* __restrict__ Wb_, const float* __restrict__ bias,
    ushort_t* __restrict__ Oh, ushort_t* __restrict__ Ol) {
    int wave = threadIdx.x >> 6, lane = threadIdx.x & 63;
    int cg = wave & 1, mg = wave >> 1;
    int rl = lane & 15, gp = lane >> 4;
    u32x4 B[4][4];
    const u32x4* Wb = (const u32x4*)Wb_;
    #pragma unroll
    for (int n = 0; n < 4; ++n)
        #pragma unroll
        for (int kk = 0; kk < 4; ++kk)
            B[n][kk] = Wb[((cg * 4 + n) * 4 + kk) * 64 + lane];
    float bs[4];
    #pragma unroll
    for (int n = 0; n < 4; ++n) bs[n] = bias[cg * 64 + n * 16 + rl];
    for (int it = 0; it < 2; ++it) {
        int cid = (blockIdx.x * 2 + it) * 2 + mg;
        if (cid >= NCHUNK) continue;
        const u32x4* ph = (const u32x4*)(Ah + (size_t)(cid * 16 + rl) * 128 + gp * 8);
        const u32x4* pl = (const u32x4*)(Al + (size_t)(cid * 16 + rl) * 128 + gp * 8);
        bf8 ah[4], al4[4];
        #pragma unroll
        for (int kk = 0; kk < 4; ++kk) {
            ah[kk]  = __builtin_bit_cast(bf8, ph[kk * 4]);
            al4[kk] = __builtin_bit_cast(bf8, pl[kk * 4]);
        }
        f4 acc[4];
        #pragma unroll
        for (int n = 0; n < 4; ++n) acc[n] = (f4)0.f;
        #pragma unroll
        for (int kk = 0; kk < 4; ++kk) {
            #pragma unroll
            for (int n = 0; n < 4; ++n)
                acc[n] = __builtin_amdgcn_mfma_f32_16x16x32_bf16(
                    ah[kk], __builtin_bit_cast(bf8, B[n][kk]), acc[n], 0, 0, 0);
            #pragma unroll
            for (int n = 0; n < 4; ++n)
                acc[n] = __builtin_amdgcn_mfma_f32_16x16x32_bf16(
                    al4[kk], __builtin_bit_cast(bf8, B[n][kk]), acc[n], 0, 0, 0);
        }
        #pragma unroll
        for (int n = 0; n < 4; ++n)
            #pragma unroll
            for (int t = 0; t < 4; ++t) {
                float v = tanh_fast(acc[n][t] + bs[n]);
                unsigned hi = f2bf(v);
                int node = cid * 16 + gp * 4 + t;
                int col = cg * 64 + n * 16 + rl;
                Oh[(size_t)node * 128 + col] = (ushort_t)hi;
                Ol[(size_t)node * 128 + col] = (ushort_t)f2bf(v - bf2f(hi));
            }
    }
}

// ---------------- G2: [P|Q] = x3 @ Wpq (+bd0 on P cols), fp32 out -------------
__global__ __launch_bounds__(256) void k_g2(
    const ushort_t* __restrict__ Ah, const ushort_t* __restrict__ Al,
    const unsigned* __restrict__ Wb_, const float* __restrict__ bd0,
    float* __restrict__ P, float* __restrict__ Qb) {
    int cg = threadIdx.x >> 6, lane = threadIdx.x & 63;
    int rl = lane & 15, gp = lane >> 4;
    u32x4 B[4][4];
    const u32x4* Wb = (const u32x4*)Wb_;
    #pragma unroll
    for (int n = 0; n < 4; ++n)
        #pragma unroll
        for (int kk = 0; kk < 4; ++kk)
            B[n][kk] = Wb[((cg * 4 + n) * 4 + kk) * 64 + lane];
    float bs[4];
    #pragma unroll
    for (int n = 0; n < 4; ++n) {
        int j = cg * 64 + n * 16 + rl;
        bs[n] = (j < 128) ? bd0[j] : 0.f;
    }
    for (int it = 0; it < 2; ++it) {
        int cid = blockIdx.x * 2 + it;
        if (cid >= NCHUNK) continue;
        const u32x4* ph = (const u32x4*)(Ah + (size_t)(cid * 16 + rl) * 128 + gp * 8);
        const u32x4* pl = (const u32x4*)(Al + (size_t)(cid * 16 + rl) * 128 + gp * 8);
        bf8 ah[4], al4[4];
        #pragma unroll
        for (int kk = 0; kk < 4; ++kk) {
            ah[kk]  = __builtin_bit_cast(bf8, ph[kk * 4]);
            al4[kk] = __builtin_bit_cast(bf8, pl[kk * 4]);
        }
        f4 acc[4];
        #pragma unroll
        for (int n = 0; n < 4; ++n) acc[n] = (f4)0.f;
        #pragma unroll
        for (int kk = 0; kk < 4; ++kk) {
            #pragma unroll
            for (int n = 0; n < 4; ++n)
                acc[n] = __builtin_amdgcn_mfma_f32_16x16x32_bf16(
                    ah[kk], __builtin_bit_cast(bf8, B[n][kk]), acc[n], 0, 0, 0);
            #pragma unroll
            for (int n = 0; n < 4; ++n)
                acc[n] = __builtin_amdgcn_mfma_f32_16x16x32_bf16(
                    al4[kk], __builtin_bit_cast(bf8, B[n][kk]), acc[n], 0, 0, 0);
        }
        #pragma unroll
        for (int n = 0; n < 4; ++n) {
            int j = cg * 64 + n * 16 + rl;
            #pragma unroll
            for (int t = 0; t < 4; ++t) {
                float v = acc[n][t] + bs[n];
                int node = cid * 16 + gp * 4 + t;
                if (j < 128) P[(size_t)node * 128 + j] = v;
                else         Qb[(size_t)node * 128 + (j - 128)] = v;
            }
        }
    }
}

// ---------------- h0 stats: per-graph sum/sumsq of tanh(P[s]+Q[d]+w*wm) ------
__global__ __launch_bounds__(256, 1) void k_h0s(
    const int* __restrict__ edges, const float* __restrict__ ea,
    const float* __restrict__ P, const float* __restrict__ Qb,
    const float* __restrict__ Wd0,
    float* __restrict__ S0, float* __restrict__ Q0s) {
    int g = blockIdx.x >> 3, tb = blockIdx.x & 7;
    int wave = threadIdx.x >> 6, lane = threadIdx.x & 63;
    int row = lane & 15, grp = lane >> 4;
    int slot = tb * 4 + wave;
    f4 wmr[4][2];
    #pragma unroll
    for (int kk = 0; kk < 4; ++kk) {
        const f4* wmp = (const f4*)(Wd0 + 16384 + kk * 32 + grp * 8);
        wmr[kk][0] = wmp[0]; wmr[kk][1] = wmp[1];
    }
    f4 s[4][2], q[4][2];
    #pragma unroll
    for (int kk = 0; kk < 4; ++kk)
        #pragma unroll
        for (int h = 0; h < 2; ++h) { s[kk][h] = (f4)0.f; q[kk][h] = (f4)0.f; }

    for (int j = 0; j < 4; ++j) {
        int tile = slot + 32 * j;
        if (tile >= 125) break;
        int eg0 = g * EPG + tile * 32;
        #pragma unroll
        for (int m = 0; m < 2; ++m) {
            int e = eg0 + 16 * m + row;
            int sn = edges[e], dn = edges[N_EDGES + e];
            float w = ea[2 * e];
            const f4* Pr = (const f4*)(P + sn * 128);
            const f4* Qr = (const f4*)(Qb + dn * 128);
            #pragma unroll
            for (int kk = 0; kk < 4; ++kk) {
                int o = kk * 8 + grp * 2;
                f4 p0 = Pr[o], p1 = Pr[o + 1];
                f4 q0 = Qr[o], q1 = Qr[o + 1];
                #pragma unroll
                for (int r = 0; r < 4; ++r) {
                    float h0 = tanh_fast(p0[r] + q0[r] + w * wmr[kk][0][r]);
                    float h1 = tanh_fast(p1[r] + q1[r] + w * wmr[kk][1][r]);
                    s[kk][0][r] += h0; q[kk][0][r] += h0 * h0;
                    s[kk][1][r] += h1; q[kk][1][r] += h1 * h1;
                }
            }
        }
    }
    #pragma unroll
    for (int kk = 0; kk < 4; ++kk)
        #pragma unroll
        for (int h = 0; h < 2; ++h)
            #pragma unroll
            for (int r = 0; r < 4; ++r) {
                float sv = s[kk][h][r], qv = q[kk][h][r];
                sv += __shfl_xor(sv, 1); sv += __shfl_xor(sv, 2);
                sv += __shfl_xor(sv, 4); sv += __shfl_xor(sv, 8);
                qv += __shfl_xor(qv, 1); qv += __shfl_xor(qv, 2);
                qv += __shfl_xor(qv, 4); qv += __shfl_xor(qv, 8);
                if (row == 0) {
                    int k = kk * 32 + grp * 8 + h * 4 + r;
                    atomicAdd(&S0[g * 128 + k], sv);
                    atomicAdd(&Q0s[g * 128 + k], qv);
                }
            }
}

// ---------------- fold gnorm0 into Wd1 -> bf16 frag-packed W1b + gam ---------
__global__ __launch_bounds__(256) void k_fin0(
    const float* __restrict__ S0, const float* __restrict__ Q0s,
    const float* __restrict__ gnw, const float* __restrict__ gnb, const float* __restrict__ gnms,
    const float* __restrict__ Wd1, const float* __restrict__ bd1,
    unsigned* __restrict__ W1b, float* __restrict__ gam) {
    int g = blockIdx.x;
    __shared__ float al[128], be[128];
    if (threadIdx.x < 128) {
        int k = threadIdx.x;
        float S = S0[g * 128 + k], Q = Q0s[g * 128 + k];
        float mean = S * (1.f / EPG);
        float t = mean * gnms[k];
        float var = (Q - 2.f * t * S) * (1.f / EPG) + t * t;
        float a = gnw[k] * rsqrtf(var + 1e-5f);
        al[k] = a;
        be[k] = gnb[k] - a * t;
    }
    __syncthreads();
    unsigned* Wb = W1b + (size_t)g * 4096;
    for (int i = threadIdx.x; i < 4096; i += 256) {
        int t = i & 3, l = (i >> 2) & 63, kk = (i >> 8) & 3, n = i >> 10;
        int k = kk * 32 + ((l >> 4) << 3) + 2 * t;
        int j = 16 * n + (l & 15);
        unsigned lo = f2bf(al[k] * Wd1[k * 64 + j]);
        unsigned hi = f2bf(al[k + 1] * Wd1[(k + 1) * 64 + j]);
        Wb[i] = lo | (hi << 16);
    }
    if (threadIdx.x < 64) {
        int j = threadIdx.x;
        float acc = bd1[j];
        #pragma unroll 8
        for (int k = 0; k < 128; ++k) acc += be[k] * Wd1[k * 64 + j];
        gam[g * 64 + j] = acc;
    }
}

// ---------------- MFMA h1 pass: stats (DO_VALS=0) or final vals (=1) ---------
template<int DO_VALS>
__global__ __launch_bounds__(256, 1) void k_h1m(
    const int* __restrict__ edges, const float* __restrict__ ea,
    const float* __restrict__ P, const float* __restrict__ Qb,
    const float* __restrict__ Wd0,
    const unsigned* __restrict__ W1b, const float* __restrict__ gam,
    const float* __restrict__ ug, const float* __restrict__ cg,
    float* __restrict__ S1, float* __restrict__ Q1s,
    float* __restrict__ vals, float* __restrict__ outp) {
    int g = blockIdx.x >> 3, tb = blockIdx.x & 7;
    int wave = threadIdx.x >> 6, lane = threadIdx.x & 63;
    int col = lane & 15, grp = lane >> 4;
    int slot = tb * 4 + wave;

    bf8 bfr[4][4];
    {
        const u32x4* Wb = (const u32x4*)(W1b + (size_t)g * 4096);
        #pragma unroll
        for (int n = 0; n < 4; ++n)
            #pragma unroll
            for (int kk = 0; kk < 4; ++kk)
                bfr[n][kk] = __builtin_bit_cast(bf8, Wb[(n * 4 + kk) * 64 + lane]);
    }
    f4 wmr[4][2];
    #pragma unroll
    for (int kk = 0; kk < 4; ++kk) {
        const f4* wmp = (const f4*)(Wd0 + 16384 + kk * 32 + grp * 8);
        wmr[kk][0] = wmp[0]; wmr[kk][1] = wmp[1];
    }
    float gamn[4], un[4] = {0.f, 0.f, 0.f, 0.f};
    #pragma unroll
    for (int n = 0; n < 4; ++n) gamn[n] = gam[g * 64 + 16 * n + col];
    float cgv = 0.f;
    if (DO_VALS) {
        #pragma unroll
        for (int n = 0; n < 4; ++n) un[n] = ug[g * 64 + 16 * n + col];
        cgv = cg[g];
    }
    float sacc[4] = {0.f, 0.f, 0.f, 0.f}, qacc[4] = {0.f, 0.f, 0.f, 0.f};

    for (int j = 0; j < 4; ++j) {
        int tile = slot + 32 * j;
        if (tile >= 125) break;
        int eg0 = g * EPG + tile * 32;
        bf8 af[2][4];
        #pragma unroll
        for (int m = 0; m < 2; ++m) {
            int e = eg0 + 16 * m + col;
            int sn = edges[e], dn = edges[N_EDGES + e];
            float w = ea[2 * e];
            const f4* Pr = (const f4*)(P + sn * 128);
            const f4* Qr = (const f4*)(Qb + dn * 128);
            #pragma unroll
            for (int kk = 0; kk < 4; ++kk) {
                int o = kk * 8 + grp * 2;
                f4 p0 = Pr[o], p1 = Pr[o + 1];
                f4 q0 = Qr[o], q1 = Qr[o + 1];
                bf8 a;
                #pragma unroll
                for (int r = 0; r < 4; ++r) {
                    float h0 = tanh_fast(p0[r] + q0[r] + w * wmr[kk][0][r]);
                    float h1 = tanh_fast(p1[r] + q1[r] + w * wmr[kk][1][r]);
                    a[r]     = (short)f2bf(h0);
                    a[4 + r] = (short)f2bf(h1);
                }
                af[m][kk] = a;
            }
        }
        f4 acc[2][4];
        #pragma unroll
        for (int m = 0; m < 2; ++m)
            #pragma unroll
            for (int n = 0; n < 4; ++n) acc[m][n] = (f4)0.f;
        #pragma unroll
        for (int kk = 0; kk < 4; ++kk)
            #pragma unroll
            for (int m = 0; m < 2; ++m)
                #pragma unroll
                for (int n = 0; n < 4; ++n)
                    acc[m][n] = __builtin_amdgcn_mfma_f32_16x16x32_bf16(
                        af[m][kk], bfr[n][kk], acc[m][n], 0, 0, 0);

        if (DO_VALS) {
            float rp[2][4];
            #pragma unroll
            for (int m = 0; m < 2; ++m)
                #pragma unroll
                for (int t = 0; t < 4; ++t) {
                    float v = 0.f;
                    #pragma unroll
                    for (int n = 0; n < 4; ++n)
                        v += un[n] * tanh_fast(acc[m][n][t] + gamn[n]);
                    v += __shfl_xor(v, 1); v += __shfl_xor(v, 2);
                    v += __shfl_xor(v, 4); v += __shfl_xor(v, 8);
                    rp[m][t] = v + cgv;
                }
            if (col == 0) {
                #pragma unroll
                for (int m = 0; m < 2; ++m)
                    #pragma unroll
                    for (int pr = 0; pr < 2; ++pr) {
                        float va = rp[m][2 * pr], vb = rp[m][2 * pr + 1];
                        int p = ((eg0 + 16 * m + grp * 4) >> 1) + pr;
                        vals[p] = fminf(va, vb);
                        outp[600000 + p] = (vb < va) ? 1.f : 0.f;
                        int e = 2 * p;
                        outp[p]          = (float)edges[e];
                        outp[200000 + p] = (float)edges[N_EDGES + e];
                    }
            }
        } else {
            #pragma unroll
            for (int m = 0; m < 2; ++m)
                #pragma unroll
                for (int n = 0; n < 4; ++n)
                    #pragma unroll
                    for (int t = 0; t < 4; ++t) {
                        float h = tanh_fast(acc[m][n][t] + gamn[n]);
                        sacc[n] += h; qacc[n] += h * h;
                    }
        }
    }
    if (!DO_VALS) {
        #pragma unroll
        for (int n = 0; n < 4; ++n) {
            float s = sacc[n], q = qacc[n];
            s += __shfl_xor(s, 16); s += __shfl_xor(s, 32);
            q += __shfl_xor(q, 16); q += __shfl_xor(q, 32);
            if (lane < 16) {
                atomicAdd(&S1[g * 64 + 16 * n + col], s);
                atomicAdd(&Q1s[g * 64 + 16 * n + col], q);
            }
        }
    }
}

// ---------------- fold gnorm1 into Wout ---------------------------------------
__global__ void k_fin1(const float* __restrict__ S1, const float* __restrict__ Q1s,
                       const float* __restrict__ gnw, const float* __restrict__ gnb,
                       const float* __restrict__ gnms,
                       const float* __restrict__ Wout, const float* __restrict__ bout,
                       float* __restrict__ ug, float* __restrict__ cg) {
    int g = blockIdx.x; int j = threadIdx.x;  // 64 threads
    float S = S1[g * 64 + j], Q = Q1s[g * 64 + j];
    float mean = S * (1.f / EPG);
    float t = mean * gnms[j];
    float var = (Q - 2.f * t * S) * (1.f / EPG) + t * t;
    float a = gnw[j] * rsqrtf(var + 1e-5f);
    float b = gnb[j] - a * t;
    ug[g * 64 + j] = a * Wout[j];
    float c = b * Wout[j];
    #pragma unroll
    for (int off = 32; off; off >>= 1) c += __shfl_xor(c, off);
    if (j == 0) cg[g] = c + bout[0];
}

// ---------------- per-graph softmax over pair-min vals ------------------------
__global__ __launch_bounds__(256) void k_softmax(const float* __restrict__ vals,
                                                 float* __restrict__ outp) {
    int g = blockIdx.x;
    __shared__ float rbuf[4], rbuf2[4];
    int t = threadIdx.x;
    const float* v = vals + g * PPG;
    float mx = -1e30f;
    for (int i = t; i < PPG; i += 256) mx = fmaxf(mx, v[i]);
    #pragma unroll
    for (int off = 32; off; off >>= 1) mx = fmaxf(mx, __shfl_xor(mx, off));
    if ((t & 63) == 0) rbuf[t >> 6] = mx;
    __syncthreads();
    mx = fmaxf(fmaxf(rbuf[0], rbuf[1]), fmaxf(rbuf[2], rbuf[3]));
    float sm = 0.f;
    for (int i = t; i < PPG; i += 256) sm += expf(v[i] - mx);
    #pragma unroll
    for (int off = 32; off; off >>= 1) sm += __shfl_xor(sm, off);
    if ((t & 63) == 0) rbuf2[t >> 6] = sm;
    __syncthreads();
    sm = rbuf2[0] + rbuf2[1] + rbuf2[2] + rbuf2[3];
    for (int i = t; i < PPG; i += 256)
        outp[400000 + g * PPG + i] = expf(v[i] - mx) / (sm + 1e-16f);
}

extern "C" void kernel_launch(void* const* d_in, const int* in_sizes, int n_in,
                              void* d_out, int out_size, void* d_ws, size_t ws_size,
                              hipStream_t stream) {
    const float* x     = (const float*)d_in[0];
    const int*   edges = (const int*)d_in[1];
    const float* ea    = (const float*)d_in[2];
    const float* Wrel0 = (const float*)d_in[6],  *brel0 = (const float*)d_in[7],  *Wroot0 = (const float*)d_in[8];
    const float* Wrel1 = (const float*)d_in[9],  *brel1 = (const float*)d_in[10], *Wroot1 = (const float*)d_in[11];
    const float* Wrel2 = (const float*)d_in[12], *brel2 = (const float*)d_in[13], *Wroot2 = (const float*)d_in[14];
    const float* Wd0 = (const float*)d_in[15],  *bd0 = (const float*)d_in[16];
    const float* gnw0 = (const float*)d_in[17], *gnb0 = (const float*)d_in[18], *gnms0 = (const float*)d_in[19];
    const float* Wd1 = (const float*)d_in[20],  *bd1 = (const float*)d_in[21];
    const float* gnw1 = (const float*)d_in[22], *gnb1 = (const float*)d_in[23], *gnms1 = (const float*)d_in[24];
    const float* Wout = (const float*)d_in[25], *bout = (const float*)d_in[26];
    float* o = (float*)d_out;
    float* w = (float*)d_ws;

    // region A [0, 8.25M): early node tensors, later reused by x3 planes
    float* agg5 = w;                               // 250000
    float* x1   = w + 250000;                      // 1.6M
    float* x2   = w + 1850000;                     // 3.2M
    ushort_t* c2h = (ushort_t*)(w + 5050000);      // 50K x 64 ushort (1.6M f)
    ushort_t* c2l = (ushort_t*)(w + 6650000);      // ends 8.25M
    ushort_t* x3h = (ushort_t*)(w + 0);            // 50K x 128 ushort (3.2M f)
    ushort_t* x3l = (ushort_t*)(w + 3200000);      // ends 6.4M  (A dead by k_g1)
    // region B [8.25M, 21.05M): cat planes then P|Qb
    float* P    = w + 8250000;                     // 6.4M
    float* Qb   = w + 14650000;                    // 6.4M
    ushort_t* cath = (ushort_t*)(w + 8250000);     // 3.2M f (alias P, dead by k_g2)
    ushort_t* catl = (ushort_t*)(w + 11450000);    // 3.2M f
    // tail
    float* tail = w + 21050000;
    unsigned* Wcb  = (unsigned*)tail;              // 8192
    unsigned* Wpqb = Wcb + 8192;                   // 16384
    unsigned* W2b  = Wpqb + 16384;                 // 2048
    int* cnt   = (int*)(W2b + 2048);               // 50000
    int* fillc = cnt + 50000;                      // 50000 (memset with cnt)
    int* offs  = fillc + 50000;                    // 50000
    int* esrc  = offs + 50000;                     // 200000
    float* ew  = (float*)(esrc + 200000);          // 200000
    float* S0  = ew + 200000;                      // 12800
    float* Q0s = S0 + 12800;                       // 12800
    unsigned* W1b = (unsigned*)(Q0s + 12800);      // 409600
    float* gam = (float*)(W1b + 409600);           // 6400
    float* S1  = gam + 6400;
    float* Q1s = S1 + 6400;
    float* ug  = Q1s + 6400;
    float* cg  = ug + 6400;
    float* vals = cg + 100;                        // 200000

    // ---- zero-init counters/stats ----
    hipMemsetAsync(cnt, 0, 100000 * sizeof(int), stream);      // cnt + fillc
    hipMemsetAsync(S0, 0, 25600 * sizeof(float), stream);      // S0 + Q0s
    hipMemsetAsync(S1, 0, 12800 * sizeof(float), stream);      // S1 + Q1s

    // ---- weight frag packing ----
    k_packWc<<<32, 256, 0, stream>>>(Wrel2, Wroot2, Wcb);
    k_packWpq<<<64, 256, 0, stream>>>(Wd0, Wpqb);
    k_packW2<<<8, 256, 0, stream>>>(Wrel1, Wroot1, W2b);

    // ---- CSR build ----
    k_csr_count<<<782, 256, 0, stream>>>(edges, cnt);
    k_csr_scan<<<N_G, 512, 0, stream>>>(cnt, offs);
    k_csr_fill<<<782, 256, 0, stream>>>(edges, ea, offs, fillc, esrc, ew);

    // ---- 3 GCN layers (gather + MFMA dense) ----
    k_gath5<<<1563, 256, 0, stream>>>(cnt, offs, esrc, ew, x, agg5);
    k_dense1<<<6250, 256, 0, stream>>>(x, agg5, Wrel0, brel0, Wroot0, x1, c2h, c2l);
    k_gath32<<<6250, 256, 0, stream>>>(cnt, offs, esrc, ew, x1, c2h, c2l);
    k_g1b<<<782, 256, 0, stream>>>(c2h, c2l, W2b, brel1, x2, cath, catl);
    k_gath64<<<12500, 256, 0, stream>>>(cnt, offs, esrc, ew, x2, cath, catl);

    // ---- x3 (MFMA) then [P|Q] (MFMA) ----
    k_g1<<<(NCHUNK + 3) / 4, 256, 0, stream>>>(cath, catl, Wcb, brel2, x3h, x3l);
    k_g2<<<(NCHUNK + 1) / 2, 256, 0, stream>>>(x3h, x3l, Wpqb, bd0, P, Qb);

    // ---- gnorm0 stats + fold ----
    k_h0s<<<N_G * 8, 256, 0, stream>>>(edges, ea, P, Qb, Wd0, S0, Q0s);
    k_fin0<<<N_G, 256, 0, stream>>>(S0, Q0s, gnw0, gnb0, gnms0, Wd1, bd1, W1b, gam);

    // ---- h1 stats (MFMA), fold gnorm1, h1 vals (MFMA) ----
    k_h1m<0><<<N_G * 8, 256, 0, stream>>>(edges, ea, P, Qb, Wd0, W1b, gam,
                                          ug, cg, S1, Q1s, vals, o);
    k_fin1<<<N_G, 64, 0, stream>>>(S1, Q1s, gnw1, gnb1, gnms1, Wout, bout, ug, cg);
    k_h1m<1><<<N_G * 8, 256, 0, stream>>>(edges, ea, P, Qb, Wd0, W1b, gam,
                                          ug, cg, S1, Q1s, vals, o);

    // ---- per-graph softmax ----
    k_softmax<<<N_G, 256, 0, stream>>>(vals, o);
}